// Round 8
// baseline (5971.603 us; speedup 1.0000x reference)
//
#include <hip/hip_runtime.h>
#include <math.h>

typedef unsigned short u16;
typedef unsigned int uint;
typedef __bf16 bf16x8 __attribute__((ext_vector_type(8)));
typedef unsigned short u16x8 __attribute__((ext_vector_type(8)));
typedef float f32x4 __attribute__((ext_vector_type(4)));

#define HWQ 16384
#define PI_F 3.14159265358979323846f

// canonical (bf16) input offsets inside ws
#define C_X     0
#define C_TOK   262144
#define C_QW    1310720
#define C_QB    1376256
#define C_WQ    1376768
#define C_WKV   1442304
#define C_WO    1704448
#define C_BO    1769984
#define C_BWW   1770496
#define C_BWB   1967104
#define C_MODW  1968640
#define C_MODB  2755072
#define C_HVW   2756608
#define C_HVB   3280896
#define C_OUTW  3281920
#define C_OUTB  3286528
#define C_TOTAL 3286537
#define CANON_PAD 3286544

// WT (transposed weights) element offsets (relative to WT base)
#define QWT_OFF  0
#define WQT_OFF  65536
#define WOT_OFF  131072
#define BWT_OFF  196608
#define MODT_OFF 393216
#define HVT_OFF  1179648

struct SrcPtrs { const void* p[16]; };

__device__ __forceinline__ float bs2f(u16 u){
  unsigned v = ((unsigned)u) << 16; float f; __builtin_memcpy(&f, &v, 4); return f;
}
__device__ __forceinline__ u16 f2bs(float f){
  unsigned v; __builtin_memcpy(&v, &f, 4);
  v = (v + 0x7fffu + ((v >> 16) & 1u)) >> 16;
  return (u16)v;
}
__device__ __forceinline__ f32x4 mfma16(bf16x8 a, bf16x8 b, f32x4 c){
  return __builtin_amdgcn_mfma_f32_16x16x32_bf16(a, b, c, 0, 0, 0);
}
__device__ __forceinline__ bf16x8 ld8(const u16* p){ return *(const bf16x8*)p; }
__device__ __forceinline__ void ld2lds(const u16* g, u16* l){
  __builtin_amdgcn_global_load_lds((__attribute__((address_space(1))) const uint*)g,
                                   (__attribute__((address_space(3))) uint*)l, 16, 0, 0);
}

// ---------------- dtype detect ----------------
__global__ void k_detect(const u16* qb_raw, unsigned* flag){
  __shared__ int cnt[256];
  int t = threadIdx.x;
  u16 u = qb_raw[2*t];
  int e = (u >> 7) & 0xFF;
  cnt[t] = (e >= 126) ? 1 : 0;
  __syncthreads();
  for (int s = 128; s > 0; s >>= 1){
    if (t < s) cnt[t] += cnt[t + s];
    __syncthreads();
  }
  if (t == 0) *flag = (cnt[0] >= 16) ? 1u : 0u;
}

// ---------------- convert inputs to canonical bf16 ----------------
__global__ __launch_bounds__(256) void k_convert(SrcPtrs sp, const unsigned* flag, u16* canon){
  const int offs[17] = {C_X,C_TOK,C_QW,C_QB,C_WQ,C_WKV,C_WO,C_BO,C_BWW,C_BWB,
                        C_MODW,C_MODB,C_HVW,C_HVB,C_OUTW,C_OUTB,C_TOTAL};
  int e = blockIdx.x * 256 + threadIdx.x;
  if (e >= C_TOTAL) return;
  int seg = 0;
  for (int i = 1; i < 16; i++) if (e >= offs[i]) seg = i;
  int local = e - offs[seg];
  if (*flag) canon[e] = f2bs(((const float*)sp.p[seg])[local]);
  else       canon[e] = ((const u16*)sp.p[seg])[local];
}

// ---------------- weight transpose ----------------
__global__ __launch_bounds__(256) void k_tr(const u16* canon, u16* WT){
  __shared__ u16 tile[32][33];
  int bid = blockIdx.x, t = threadIdx.x;
  const u16* src; u16* dst; int K, N, tl;
  if (bid < 384){
    int m = bid >> 6; tl = bid & 63;
    if (m == 0){ src = canon + C_QW;  dst = WT + QWT_OFF; K = 128; N = 512; }
    else if (m == 1){ src = canon + C_WQ; dst = WT + WQT_OFF; K = 512; N = 128; }
    else if (m == 2){ src = canon + C_WO; dst = WT + WOT_OFF; K = 128; N = 512; }
    else { src = canon + C_BWW + (m-3)*65536; dst = WT + BWT_OFF + (m-3)*65536; K = 128; N = 512; }
  } else if (bid < 1152){
    int m = (bid - 384) >> 8; tl = (bid - 384) & 255;
    src = canon + C_MODW + m*262144; dst = WT + MODT_OFF + m*262144; K = 512; N = 512;
  } else {
    int m = (bid - 1152) >> 8; tl = (bid - 1152) & 255;
    src = canon + C_HVW + m*262144; dst = WT + HVT_OFF + m*262144; K = 512; N = 512;
  }
  int kt = K >> 5;
  int k0 = (tl % kt) * 32, n0 = (tl / kt) * 32;
  int tx = t & 31, ty = t >> 5;
  for (int r = 0; r < 4; r++)
    tile[ty + r*8][tx] = src[(size_t)(k0 + ty + r*8) * N + n0 + tx];
  __syncthreads();
  for (int r = 0; r < 4; r++)
    dst[(size_t)(n0 + ty + r*8) * K + k0 + tx] = tile[tx][ty + r*8];
}

// ---------------- kv = tokens @ Wkv ----------------
__global__ __launch_bounds__(256) void k_kv(const u16* canon, u16* kpart, u16* vT){
  int b = blockIdx.x >> 8, kk = blockIdx.x & 255, t = threadIdx.x;
  const u16* tok = canon + C_TOK;
  const u16* Wkv = canon + C_WKV;
  __shared__ float tk[512];
  const u16* tr = tok + ((size_t)(b*256 + kk)) * 512;
  tk[t] = bs2f(tr[t]); tk[t+256] = bs2f(tr[t+256]);
  __syncthreads();
  float acc = 0.f;
  for (int k = 0; k < 512; k++) acc += tk[k] * bs2f(Wkv[k*256 + t]);
  if (t < 128) kpart[((size_t)(b*256 + kk))*128 + t] = f2bs(acc);
  else vT[((size_t)b*128 + (t-128))*256 + kk] = f2bs(acc);
}

// ---------------- per-query: gamma -> xq -> qvec ; h_l bands ----------------
__global__ __launch_bounds__(256) void k_query(const u16* canon, const float* xraw,
      const unsigned* flag, const u16* WT, u16* qvecB, u16* hlB){
  int t = threadIdx.x, q0 = blockIdx.x * 16;
  const u16* q_b = canon + C_QB;
  const u16* bw_b= canon + C_BWB;
  int lane = t & 63, wv = t >> 6, l15 = lane & 15, q4 = lane >> 4;
  __shared__ __align__(16) u16 g[16*136];
  __shared__ __align__(16) u16 xql[16*520];
  __shared__ float cco[32];
  __shared__ float omg[32];
  for (int e = t; e < 16*136; e += 256) g[e] = 0;
  for (int e = t; e < 16*520; e += 256) xql[e] = 0;
  if (t < 32) cco[t] = (*flag) ? xraw[q0*2 + t] : bs2f(canon[C_X + q0*2 + t]);
  if (t < 32) omg[t] = (float)pow(10.0, 1.0 + t * ((2.1072099696478683 - 1.0)/31.0));
  __syncthreads();
  for (int i = 0; i < 8; i++){
    int id = i*256 + t, qi = id >> 7, f = id & 127;
    int d = f >> 6, r = f & 63, fi = r & 31;
    float arg = PI_F * cco[qi*2 + d] * omg[fi];
    g[qi*136 + f] = f2bs((r < 32) ? sinf(arg) : cosf(arg));
  }
  __syncthreads();
  { // xq = relu(g @ q_W + q_b) -> xql
    const u16* Bm = WT + QWT_OFF;
    for (int nt = 0; nt < 8; nt++){
      f32x4 acc = {0.f,0.f,0.f,0.f};
      int c = wv*128 + nt*16 + l15;
      for (int ks = 0; ks < 4; ks++){
        bf16x8 a  = ld8(g + l15*136 + ks*32 + q4*8);
        bf16x8 bb = ld8(Bm + (size_t)c*128 + ks*32 + q4*8);
        acc = mfma16(a, bb, acc);
      }
      float qb = bs2f(q_b[c]);
      for (int rg = 0; rg < 4; rg++){
        int row = q4*4 + rg;
        xql[row*520 + c] = f2bs(fmaxf(acc[rg] + qb, 0.f));
      }
    }
  }
  __syncthreads();
  { // qvec = xq @ Wq -> stage in g -> coalesced store
    const u16* Bm = WT + WQT_OFF;
    for (int nh = 0; nh < 2; nh++){
      f32x4 acc = {0.f,0.f,0.f,0.f};
      int c = wv*32 + nh*16 + l15;
      for (int ks = 0; ks < 16; ks++){
        bf16x8 a  = ld8(xql + l15*520 + ks*32 + q4*8);
        bf16x8 bb = ld8(Bm + (size_t)c*512 + ks*32 + q4*8);
        acc = mfma16(a, bb, acc);
      }
      for (int rg = 0; rg < 4; rg++)
        g[(q4*4 + rg)*128 + c] = f2bs(acc[rg]);
    }
    __syncthreads();
    {
      int rr = t >> 4, cc = (t & 15)*8;
      *(u16x8*)(qvecB + (size_t)(q0 + rr)*128 + cc) = *(const u16x8*)(g + rr*128 + cc);
    }
  }
  const double LG[3] = {1.2041199826559248, 1.8061799739838869, 2.4082399653118496};
  for (int ib = 0; ib < 3; ib++){
    __syncthreads();
    if (t < 32) omg[t] = (float)pow(10.0, 1.0 + t * ((LG[ib] - 1.0)/31.0));
    __syncthreads();
    for (int i = 0; i < 8; i++){
      int id = i*256 + t, qi = id >> 7, f = id & 127;
      int d = f >> 6, r = f & 63, fi = r & 31;
      float arg = PI_F * cco[qi*2 + d] * omg[fi];
      g[qi*136 + f] = f2bs((r < 32) ? sinf(arg) : cosf(arg));
    }
    __syncthreads();
    const u16* Bm = WT + BWT_OFF + ib*65536;
    for (int nt = 0; nt < 8; nt++){
      f32x4 acc = {0.f,0.f,0.f,0.f};
      int c = wv*128 + nt*16 + l15;
      for (int ks = 0; ks < 4; ks++){
        bf16x8 a  = ld8(g + l15*136 + ks*32 + q4*8);
        bf16x8 bb = ld8(Bm + (size_t)c*128 + ks*32 + q4*8);
        acc = mfma16(a, bb, acc);
      }
      float bias = bs2f(bw_b[ib*512 + c]);
      for (int rg = 0; rg < 4; rg++)
        xql[(q4*4 + rg)*520 + c] = f2bs(fmaxf(acc[rg] + bias, 0.f));
    }
    __syncthreads();
    for (int it = 0; it < 4; it++){
      int rr = it*4 + (t >> 6), cc = (t & 63)*8;
      *(u16x8*)(hlB + ((size_t)ib*HWQ + q0 + rr)*512 + cc) = *(const u16x8*)(xql + rr*520 + cc);
    }
  }
}

// ---------------- attention + mod projection (f32 softmax, staged store) ----------------
__global__ __launch_bounds__(256) void k_attn(const u16* canon, const float* xraw,
      const unsigned* flag, const u16* qvecB, const u16* kpart, const u16* vT,
      const u16* WT, u16* modB){
  int t = threadIdx.x;
  int b = blockIdx.x & 7, qt = blockIdx.x >> 3, q0 = qt*32;
  const u16* bo = canon + C_BO;
  int lane = t & 63, wv = t >> 6, l15 = lane & 15, q4 = lane >> 4;
  __shared__ __align__(16) u16 ql[32*136];
  __shared__ __align__(16) u16 pl[32*264];
  __shared__ __align__(16) float pf[32*264];
  __shared__ __align__(16) u16 ot[32*136];
  __shared__ float tqs[32];
  __shared__ float red[256];
  __shared__ float rst[32];
  for (int e = t; e < 32*136; e += 256){ ql[e] = 0; ot[e] = 0; }
  for (int e = t; e < 32*264; e += 256) pl[e] = 0;
  __syncthreads();
  for (int i = 0; i < 16; i++){
    int id = i*256 + t, qi = id >> 7, c = id & 127;
    ql[qi*136 + c] = qvecB[(size_t)(q0 + qi)*128 + c];
  }
  if (t < 32){
    float c0, c1;
    if (*flag){ c0 = xraw[(q0+t)*2]; c1 = xraw[(q0+t)*2 + 1]; }
    else { c0 = bs2f(canon[C_X + (q0+t)*2]); c1 = bs2f(canon[C_X + (q0+t)*2 + 1]); }
    int rr = (int)(c0*16.f), cc = (int)(c1*16.f);
    tqs[t] = (float)(rr*16 + cc) * (1.f/256.f);
  }
  __syncthreads();
  for (int h = 0; h < 2; h++){
    f32x4 sac[2][4];
    for (int mt = 0; mt < 2; mt++) for (int nt = 0; nt < 4; nt++) sac[mt][nt] = (f32x4){0.f,0.f,0.f,0.f};
    const u16* kb = kpart + (size_t)b*256*128 + h*64;
    for (int ks = 0; ks < 2; ks++){
      bf16x8 a0 = ld8(ql + l15*136 + h*64 + ks*32 + q4*8);
      bf16x8 a1 = ld8(ql + (16+l15)*136 + h*64 + ks*32 + q4*8);
      for (int nt = 0; nt < 4; nt++){
        int kk = wv*64 + nt*16 + l15;
        bf16x8 bb = ld8(kb + (size_t)kk*128 + ks*32 + q4*8);
        sac[0][nt] = mfma16(a0, bb, sac[0][nt]);
        sac[1][nt] = mfma16(a1, bb, sac[1][nt]);
      }
    }
    for (int mt = 0; mt < 2; mt++) for (int nt = 0; nt < 4; nt++){
      int kk = wv*64 + nt*16 + l15;
      float pos = ((float)kk + 0.5f) * (1.f/256.f);
      for (int rg = 0; rg < 4; rg++){
        int row = mt*16 + q4*4 + rg;
        float dd = tqs[row] - pos;
        pf[row*264 + kk] = sac[mt][nt][rg]*0.125f - 10.f*dd*dd;
      }
    }
    __syncthreads();
    {
      int r = t >> 3, i = t & 7;
      float* pr = pf + r*264 + i*32;
      u16* po = pl + r*264 + i*32;
      float m = -1e30f;
      for (int j = 0; j < 32; j++) m = fmaxf(m, pr[j]);
      red[t] = m;
      __syncthreads();
      if (t < 32){ float mm = red[t*8];
        for (int j = 1; j < 8; j++) mm = fmaxf(mm, red[t*8+j]);
        rst[t] = mm; }
      __syncthreads();
      float mm = rst[r], sum = 0.f;
      for (int j = 0; j < 32; j++){ float e = expf(pr[j] - mm); pr[j] = e; sum += e; }
      red[t] = sum;
      __syncthreads();
      if (t < 32){ float ss = 0.f;
        for (int j = 0; j < 8; j++) ss += red[t*8+j];
        rst[t] = 1.f/ss; }
      __syncthreads();
      float inv = rst[r];
      for (int j = 0; j < 32; j++) po[j] = f2bs(pr[j] * inv);
    }
    __syncthreads();
    f32x4 oac[2] = {(f32x4){0.f,0.f,0.f,0.f}, (f32x4){0.f,0.f,0.f,0.f}};
    const u16* vb = vT + ((size_t)b*128 + h*64)*256;
    int dl = wv*16 + l15;
    for (int ks = 0; ks < 8; ks++){
      bf16x8 a0 = ld8(pl + l15*264 + ks*32 + q4*8);
      bf16x8 a1 = ld8(pl + (16+l15)*264 + ks*32 + q4*8);
      bf16x8 bb = ld8(vb + (size_t)dl*256 + ks*32 + q4*8);
      oac[0] = mfma16(a0, bb, oac[0]);
      oac[1] = mfma16(a1, bb, oac[1]);
    }
    for (int mt = 0; mt < 2; mt++) for (int rg = 0; rg < 4; rg++){
      int row = mt*16 + q4*4 + rg;
      ot[row*136 + h*64 + dl] = f2bs(oac[mt][rg]);
    }
    __syncthreads();
  }
  // mod = ot @ Wo + bo : stage into pf (as u16) then coalesced store
  u16* stg = (u16*)pf;
  const u16* wob = WT + WOT_OFF;
  for (int nt = 0; nt < 8; nt++){
    f32x4 mac[2] = {(f32x4){0.f,0.f,0.f,0.f}, (f32x4){0.f,0.f,0.f,0.f}};
    int c = wv*128 + nt*16 + l15;
    for (int ks = 0; ks < 4; ks++){
      bf16x8 a0 = ld8(ot + l15*136 + ks*32 + q4*8);
      bf16x8 a1 = ld8(ot + (16+l15)*136 + ks*32 + q4*8);
      bf16x8 bb = ld8(wob + (size_t)c*128 + ks*32 + q4*8);
      mac[0] = mfma16(a0, bb, mac[0]);
      mac[1] = mfma16(a1, bb, mac[1]);
    }
    float bv = bs2f(bo[c]);
    for (int mt = 0; mt < 2; mt++) for (int rg = 0; rg < 4; rg++){
      int row = mt*16 + q4*4 + rg;
      stg[row*512 + c] = f2bs(mac[mt][rg] + bv);
    }
  }
  __syncthreads();
  for (int it = 0; it < 8; it++){
    int rr = it*4 + (t >> 6), cc = (t & 63)*8;
    *(u16x8*)(modB + ((size_t)(q0+rr)*8 + b)*512 + cc) = *(const u16x8*)(stg + rr*512 + cc);
  }
}

// ================= FAST PATH: m97-style GEMM, chunked over M, staged stores =================
__global__ __launch_bounds__(256) void k_gemm(const u16* A, const u16* BW, const u16* canon,
      int biasOff, const u16* hl, const u16* res, u16* Xout, int owPrev, int owCur,
      float* totf, int gr0){
  __shared__ __align__(16) u16 sh[8192];   // As=sh[0..4095], Bs=sh[4096..8191]; epilogue staging
  int t = threadIdx.x;
  int rb = blockIdx.x >> 2, cb = blockIdx.x & 3;
  int r0 = rb*128, c0 = cb*128;
  int lane = t & 63, w = t >> 6, l15 = lane & 15, q4 = lane >> 4;
  int wm = w >> 1, wn = w & 1;
  int rsub = w*16 + (lane >> 2);
  int ksub = (lane & 3)*8;
  f32x4 acc[4][4];
  for (int mt = 0; mt < 4; mt++) for (int nt = 0; nt < 4; nt++) acc[mt][nt] = (f32x4){0.f,0.f,0.f,0.f};
  const u16* ga = A + (size_t)(r0 + rsub)*512 + ksub;
  const u16* gb = BW + (size_t)(c0 + rsub)*512 + ksub;
  u16* la0 = sh + w*512 + lane*8;
  u16* lb0 = sh + 4096 + w*512 + lane*8;
  for (int ks = 0; ks < 16; ks++){
    int k0 = ks*32;
    __syncthreads();
    ld2lds(ga + k0, la0);
    ld2lds(ga + 64*512 + k0, la0 + 2048);
    ld2lds(gb + k0, lb0);
    ld2lds(gb + 64*512 + k0, lb0 + 2048);
    __syncthreads();
    bf16x8 af[4], bfr[4];
    for (int mt = 0; mt < 4; mt++) af[mt]  = ld8(sh + (wm*64 + mt*16 + l15)*32 + q4*8);
    for (int nt = 0; nt < 4; nt++) bfr[nt] = ld8(sh + 4096 + (wn*64 + nt*16 + l15)*32 + q4*8);
    for (int mt = 0; mt < 4; mt++)
      for (int nt = 0; nt < 4; nt++)
        acc[mt][nt] = mfma16(af[mt], bfr[nt], acc[mt][nt]);
  }
  // epilogue: bias/hl/relu/res + proj atomics; output staged in LDS, coalesced store
  float biasv[4];
  for (int nt = 0; nt < 4; nt++)
    biasv[nt] = bs2f(canon[biasOff + c0 + wn*64 + nt*16 + l15]);
  float owv[4][3];
  int owi = (owPrev >= 0) ? owPrev : owCur;
  if (owi >= 0){
    for (int nt = 0; nt < 4; nt++){
      int c = c0 + wn*64 + nt*16 + l15;
      for (int o = 0; o < 3; o++)
        owv[nt][o] = bs2f(canon[C_OUTW + owi*1536 + c*3 + o]);
    }
  }
  for (int half = 0; half < 2; half++){
    __syncthreads();
    if (wm == half){
      for (int mt = 0; mt < 4; mt++){
        for (int rg = 0; rg < 4; rg++){
          int rloc = r0 + half*64 + mt*16 + q4*4 + rg;
          int gr = gr0 + rloc;
          float p0 = 0.f, p1 = 0.f, p2 = 0.f;
          for (int nt = 0; nt < 4; nt++){
            int c = c0 + wn*64 + nt*16 + l15;
            float v = acc[mt][nt][rg] + biasv[nt];
            if (hl) v += bs2f(hl[(size_t)(gr >> 3)*512 + c]);
            v = fmaxf(v, 0.f);
            float pv = v;
            if (res){
              float xp = bs2f(res[(size_t)rloc*512 + c]);
              v += xp;
              pv = xp;
            }
            sh[(mt*16 + q4*4 + rg)*128 + wn*64 + nt*16 + l15] = f2bs(v);
            if (owi >= 0){
              p0 += pv*owv[nt][0]; p1 += pv*owv[nt][1]; p2 += pv*owv[nt][2];
            }
          }
          if (owi >= 0){
            for (int m = 1; m < 16; m <<= 1){
              p0 += __shfl_xor(p0, m, 64);
              p1 += __shfl_xor(p1, m, 64);
              p2 += __shfl_xor(p2, m, 64);
            }
            if (l15 == 0){
              atomicAdd(totf + (size_t)gr*3 + 0, p0);
              atomicAdd(totf + (size_t)gr*3 + 1, p1);
              atomicAdd(totf + (size_t)gr*3 + 2, p2);
            }
          }
        }
      }
    }
    __syncthreads();
    if (Xout){
      for (int it = 0; it < 4; it++){
        int rr = it*16 + (t >> 4), cc = (t & 15)*8;
        *(u16x8*)(Xout + (size_t)(r0 + half*64 + rr)*512 + c0 + cc) = *(const u16x8*)(sh + rr*128 + cc);
      }
    }
  }
}

__global__ __launch_bounds__(256) void k_zero(const u16* canon, float* totf){
  int e = blockIdx.x*256 + threadIdx.x;
  if (e >= 393216) return;
  int o = e - (e/3)*3;
  totf[e] = bs2f(canon[C_OUTB + o]) + bs2f(canon[C_OUTB + 3 + o]) + bs2f(canon[C_OUTB + 6 + o]);
}

__global__ __launch_bounds__(256) void k_finish(const float* totf, const unsigned* flag, void* outv){
  int e = blockIdx.x*256 + threadIdx.x;
  if (e >= 393216) return;
  int o = e - (e/3)*3;
  int pos = e/3;
  int b = pos >> 14, q = pos & 16383;
  float v = totf[((q << 3) + b)*3 + o];
  if (*flag) ((float*)outv)[e] = v;
  else       ((u16*)outv)[e]   = f2bs(v);
}

// ================= FALLBACK PATH (round-5 fused k_bands) =================
__device__ __forceinline__ void do_gemm(
    int aglob, const u16* Ag, const u16* Al,
    const u16* Bm, u16* bsl,
    int mode, const u16* biasv, const u16* hlrow,
    u16* Xw, const u16* Xr, int t)
{
  int lane = t & 63, wv = t >> 6, wm = wv >> 1, wn = wv & 1;
  int l15 = lane & 15, q4 = lane >> 4;
  for (int nb = 0; nb < 4; nb++){
    f32x4 acc[2][4];
    for (int mt = 0; mt < 2; mt++) for (int nt = 0; nt < 4; nt++) acc[mt][nt] = (f32x4){0.f,0.f,0.f,0.f};
    for (int ks = 0; ks < 16; ks++){
      __syncthreads();
      {
        int c0 = t, c1 = t + 256;
        u16x8 v0 = *(const u16x8*)(Bm + (size_t)(nb*128 + (c0>>2))*512 + ks*32 + (c0&3)*8);
        u16x8 v1 = *(const u16x8*)(Bm + (size_t)(nb*128 + (c1>>2))*512 + ks*32 + (c1&3)*8);
        *(u16x8*)(bsl + (c0>>2)*40 + (c0&3)*8) = v0;
        *(u16x8*)(bsl + (c1>>2)*40 + (c1&3)*8) = v1;
      }
      __syncthreads();
      bf16x8 a0, a1;
      if (aglob){
        a0 = ld8(Ag + (size_t)(wm*32 + l15)*512 + ks*32 + q4*8);
        a1 = ld8(Ag + (size_t)(wm*32 + 16 + l15)*512 + ks*32 + q4*8);
      } else {
        a0 = ld8(Al + (wm*32 + l15)*520 + ks*32 + q4*8);
        a1 = ld8(Al + (wm*32 + 16 + l15)*520 + ks*32 + q4*8);
      }
      for (int nt = 0; nt < 4; nt++){
        bf16x8 bb = ld8(bsl + (wn*64 + nt*16 + l15)*40 + q4*8);
        acc[0][nt] = mfma16(a0, bb, acc[0][nt]);
        acc[1][nt] = mfma16(a1, bb, acc[1][nt]);
      }
    }
    __syncthreads();
    for (int mt = 0; mt < 2; mt++) for (int nt = 0; nt < 4; nt++){
      int col = nb*128 + wn*64 + nt*16 + l15;
      float bias = bs2f(biasv[col]);
      for (int rg = 0; rg < 4; rg++){
        int row = wm*32 + mt*16 + q4*4 + rg;
        float v = acc[mt][nt][rg] + bias;
        if (mode <= 1) v += bs2f(hlrow[(size_t)(row >> 3)*512 + col]);
        v = fmaxf(v, 0.f);
        if (mode == 1) v += bs2f(Xr[row*520 + col]);
        Xw[row*520 + col] = f2bs(v);
      }
    }
  }
}

__device__ __forceinline__ void proj(int i, const u16* X, const u16* outW, const u16* outb,
                                     u16* bsl, float* totv, int t){
  float* owf = (float*)bsl;
  for (int e = t; e < 1536; e += 256) owf[e] = bs2f(outW[i*1536 + e]);
  __syncthreads();
  if (t < 192){
    int r = t/3, o = t - (t/3)*3;
    float s = bs2f(outb[i*3 + o]);
    const u16* xr = X + r*520;
    for (int c = 0; c < 512; c++) s += bs2f(xr[c]) * owf[c*3 + o];
    *totv += s;
  }
  __syncthreads();
}

__global__ __launch_bounds__(256) void k_bands(const u16* canon, const u16* modB,
      const u16* WT, const u16* hlB, const unsigned* flag, void* outv){
  int t = threadIdx.x;
  int rgp = blockIdx.x, q0 = rgp*8;
  const u16* mod_b = canon + C_MODB;
  const u16* hv_b  = canon + C_HVB;
  const u16* outW  = canon + C_OUTW;
  const u16* outb  = canon + C_OUTB;
  __shared__ __align__(16) u16 xa[64*520];
  __shared__ __align__(16) u16 xb[64*520];
  __shared__ __align__(16) u16 bsl[5120];
  for (int e = t; e < 64*520; e += 256){ xa[e] = 0; xb[e] = 0; }
  for (int e = t; e < 5120; e += 256) bsl[e] = 0;
  __syncthreads();
  const u16* Ag = modB + (size_t)rgp*64*512;
  float totv = 0.f;
  do_gemm(1, Ag, 0, WT + MODT_OFF, bsl, 0, mod_b, hlB + (size_t)q0*512, xa, 0, t);
  __syncthreads();
  proj(0, xa, outW, outb, bsl, &totv, t);
  do_gemm(1, Ag, 0, WT + MODT_OFF + 262144, bsl, 1, mod_b + 512, hlB + (size_t)(HWQ + q0)*512, xb, xa, t);
  __syncthreads();
  do_gemm(0, 0, xb, WT + HVT_OFF, bsl, 2, hv_b, 0, xa, 0, t);
  __syncthreads();
  proj(1, xa, outW, outb, bsl, &totv, t);
  do_gemm(1, Ag, 0, WT + MODT_OFF + 524288, bsl, 1, mod_b + 1024, hlB + (size_t)(2*HWQ + q0)*512, xb, xa, t);
  __syncthreads();
  do_gemm(0, 0, xb, WT + HVT_OFF + 262144, bsl, 2, hv_b + 512, 0, xa, 0, t);
  __syncthreads();
  proj(2, xa, outW, outb, bsl, &totv, t);
  if (t < 192){
    int r = t/3, o = t - (t/3)*3;
    int bb2 = r & 7, qq = q0 + (r >> 3);
    size_t idx = ((size_t)bb2*HWQ + qq)*3 + o;
    if (*flag) ((float*)outv)[idx] = totv;
    else       ((u16*)outv)[idx]   = f2bs(totv);
  }
}

extern "C" void kernel_launch(void* const* d_in, const int* in_sizes, int n_in,
                              void* d_out, int out_size, void* d_ws, size_t ws_size,
                              hipStream_t stream){
  (void)in_sizes; (void)n_in; (void)out_size;

  u16* wsp   = (u16*)d_ws;
  unsigned* flag = (unsigned*)wsp;
  u16* canon = wsp + 8;
  u16* WT    = canon + CANON_PAD;
  u16* kpart = WT + 1703936;
  u16* vT    = kpart + 262144;
  u16* qvecB = vT + 262144;            // dead after k_attn; totf overlays it
  u16* hlB   = qvecB + 2097152;
  u16* modB  = hlB + 25165824;
  u16* XA    = modB + 67108864;        // chunk buffers (fast path only)
  float* totf = (float*)qvecB;
  if (ws_size < 199773250ULL) return;

  // chunk choice: prefer 32768 (chunk working set ~115 MB fits 256 MB L3)
  const size_t baseB = 199773232ULL;
  int CH = 0;
  const int cands[3] = {32768, 16384, 8192};
  for (int i = 0; i < 3; i++){
    if (baseB + (size_t)2*cands[i]*512*2 <= ws_size){ CH = cands[i]; break; }
  }

  SrcPtrs sp;
  for (int i = 0; i < 16; i++) sp.p[i] = d_in[i];
  const float* xraw = (const float*)d_in[0];

  k_detect <<<1, 256, 0, stream>>>((const u16*)d_in[3], flag);
  k_convert<<<(C_TOTAL + 255)/256, 256, 0, stream>>>(sp, flag, canon);
  k_tr     <<<1664, 256, 0, stream>>>(canon, WT);
  k_kv     <<<2048, 256, 0, stream>>>(canon, kpart, vT);
  k_query  <<<1024, 256, 0, stream>>>(canon, xraw, flag, WT, qvecB, hlB);
  k_attn   <<<4096, 256, 0, stream>>>(canon, xraw, flag, qvecB, kpart, vT, WT, modB);

  if (CH > 0){
    u16* XB = XA + (size_t)CH*512;
    const u16* MOD0 = WT + MODT_OFF;
    const u16* MOD1 = WT + MODT_OFF + 262144;
    const u16* MOD2 = WT + MODT_OFF + 524288;
    const u16* HV0  = WT + HVT_OFF;
    const u16* HV1  = WT + HVT_OFF + 262144;
    k_zero<<<1536, 256, 0, stream>>>(canon, totf);
    int grid = (CH/128)*4;
    for (int off = 0; off < 131072; off += CH){
      const u16* Ac = modB + (size_t)off*512;
      // g1: X1 = relu(mod@W0 + b0 + hl0)
      k_gemm<<<grid, 256, 0, stream>>>(Ac, MOD0, canon, C_MODB,        hlB,                    (const u16*)0, XA, -1, -1, totf, off);
      // g2: X2 = relu(mod@W1 + b1 + hl1) + X1 ; proj X1 w/ outW0
      k_gemm<<<grid, 256, 0, stream>>>(Ac, MOD1, canon, C_MODB + 512,  hlB + (size_t)HWQ*512,  XA,            XB,  0, -1, totf, off);
      // g3: X3 = relu(X2@hv0 + hvb0)
      k_gemm<<<grid, 256, 0, stream>>>(XB, HV0,  canon, C_HVB,         (const u16*)0,          (const u16*)0, XA, -1, -1, totf, off);
      // g4: X4 = relu(mod@W2 + b2 + hl2) + X3 ; proj X3 w/ outW1
      k_gemm<<<grid, 256, 0, stream>>>(Ac, MOD2, canon, C_MODB + 1024, hlB + (size_t)2*HWQ*512, XA,           XB,  1, -1, totf, off);
      // g5: X5 = relu(X4@hv1 + hvb1) ; proj X5 w/ outW2 (no store)
      k_gemm<<<grid, 256, 0, stream>>>(XB, HV1,  canon, C_HVB + 512,   (const u16*)0,          (const u16*)0, (u16*)0, -1, 2, totf, off);
    }
    k_finish<<<1536, 256, 0, stream>>>(totf, flag, d_out);
  } else {
    k_bands<<<2048, 256, 0, stream>>>(canon, modB, WT, hlB, flag, d_out);
  }
}

// Round 10
// 1775.147 us; speedup vs baseline: 3.3640x; 3.3640x over previous
//
#include <hip/hip_runtime.h>
#include <math.h>

typedef unsigned short u16;
typedef unsigned int uint;
typedef __bf16 bf16x8 __attribute__((ext_vector_type(8)));
typedef unsigned short u16x8 __attribute__((ext_vector_type(8)));
typedef float f32x4 __attribute__((ext_vector_type(4)));

#define HWQ 16384
#define PI_F 3.14159265358979323846f

// canonical (bf16) input offsets inside ws
#define C_X     0
#define C_TOK   262144
#define C_QW    1310720
#define C_QB    1376256
#define C_WQ    1376768
#define C_WKV   1442304
#define C_WO    1704448
#define C_BO    1769984
#define C_BWW   1770496
#define C_BWB   1967104
#define C_MODW  1968640
#define C_MODB  2755072
#define C_HVW   2756608
#define C_HVB   3280896
#define C_OUTW  3281920
#define C_OUTB  3286528
#define C_TOTAL 3286537
#define CANON_PAD 3286544

// WT (transposed weights) element offsets (relative to WT base)
#define QWT_OFF  0
#define WQT_OFF  65536
#define WOT_OFF  131072
#define BWT_OFF  196608
#define MODT_OFF 393216
#define HVT_OFF  1179648

struct SrcPtrs { const void* p[16]; };

__device__ __forceinline__ float bs2f(u16 u){
  unsigned v = ((unsigned)u) << 16; float f; __builtin_memcpy(&f, &v, 4); return f;
}
__device__ __forceinline__ u16 f2bs(float f){
  unsigned v; __builtin_memcpy(&v, &f, 4);
  v = (v + 0x7fffu + ((v >> 16) & 1u)) >> 16;
  return (u16)v;
}
__device__ __forceinline__ f32x4 mfma16(bf16x8 a, bf16x8 b, f32x4 c){
  return __builtin_amdgcn_mfma_f32_16x16x32_bf16(a, b, c, 0, 0, 0);
}
__device__ __forceinline__ bf16x8 ld8(const u16* p){ return *(const bf16x8*)p; }

// ---------------- dtype detect ----------------
__global__ void k_detect(const u16* qb_raw, unsigned* flag){
  __shared__ int cnt[256];
  int t = threadIdx.x;
  u16 u = qb_raw[2*t];
  int e = (u >> 7) & 0xFF;
  cnt[t] = (e >= 126) ? 1 : 0;
  __syncthreads();
  for (int s = 128; s > 0; s >>= 1){
    if (t < s) cnt[t] += cnt[t + s];
    __syncthreads();
  }
  if (t == 0) *flag = (cnt[0] >= 16) ? 1u : 0u;
}

// ---------------- convert inputs to canonical bf16 ----------------
__global__ __launch_bounds__(256) void k_convert(SrcPtrs sp, const unsigned* flag, u16* canon){
  const int offs[17] = {C_X,C_TOK,C_QW,C_QB,C_WQ,C_WKV,C_WO,C_BO,C_BWW,C_BWB,
                        C_MODW,C_MODB,C_HVW,C_HVB,C_OUTW,C_OUTB,C_TOTAL};
  int e = blockIdx.x * 256 + threadIdx.x;
  if (e >= C_TOTAL) return;
  int seg = 0;
  for (int i = 1; i < 16; i++) if (e >= offs[i]) seg = i;
  int local = e - offs[seg];
  if (*flag) canon[e] = f2bs(((const float*)sp.p[seg])[local]);
  else       canon[e] = ((const u16*)sp.p[seg])[local];
}

// ---------------- weight transpose ----------------
__global__ __launch_bounds__(256) void k_tr(const u16* canon, u16* WT){
  __shared__ u16 tile[32][33];
  int bid = blockIdx.x, t = threadIdx.x;
  const u16* src; u16* dst; int K, N, tl;
  if (bid < 384){
    int m = bid >> 6; tl = bid & 63;
    if (m == 0){ src = canon + C_QW;  dst = WT + QWT_OFF; K = 128; N = 512; }
    else if (m == 1){ src = canon + C_WQ; dst = WT + WQT_OFF; K = 512; N = 128; }
    else if (m == 2){ src = canon + C_WO; dst = WT + WOT_OFF; K = 128; N = 512; }
    else { src = canon + C_BWW + (m-3)*65536; dst = WT + BWT_OFF + (m-3)*65536; K = 128; N = 512; }
  } else if (bid < 1152){
    int m = (bid - 384) >> 8; tl = (bid - 384) & 255;
    src = canon + C_MODW + m*262144; dst = WT + MODT_OFF + m*262144; K = 512; N = 512;
  } else {
    int m = (bid - 1152) >> 8; tl = (bid - 1152) & 255;
    src = canon + C_HVW + m*262144; dst = WT + HVT_OFF + m*262144; K = 512; N = 512;
  }
  int kt = K >> 5;
  int k0 = (tl % kt) * 32, n0 = (tl / kt) * 32;
  int tx = t & 31, ty = t >> 5;
  for (int r = 0; r < 4; r++)
    tile[ty + r*8][tx] = src[(size_t)(k0 + ty + r*8) * N + n0 + tx];
  __syncthreads();
  for (int r = 0; r < 4; r++)
    dst[(size_t)(n0 + ty + r*8) * K + k0 + tx] = tile[tx][ty + r*8];
}

// ---------------- kv = tokens @ Wkv ----------------
__global__ __launch_bounds__(256) void k_kv(const u16* canon, u16* kpart, u16* vT){
  int b = blockIdx.x >> 8, kk = blockIdx.x & 255, t = threadIdx.x;
  const u16* tok = canon + C_TOK;
  const u16* Wkv = canon + C_WKV;
  __shared__ float tk[512];
  const u16* tr = tok + ((size_t)(b*256 + kk)) * 512;
  tk[t] = bs2f(tr[t]); tk[t+256] = bs2f(tr[t+256]);
  __syncthreads();
  float acc = 0.f;
  for (int k = 0; k < 512; k++) acc += tk[k] * bs2f(Wkv[k*256 + t]);
  if (t < 128) kpart[((size_t)(b*256 + kk))*128 + t] = f2bs(acc);
  else vT[((size_t)b*128 + (t-128))*256 + kk] = f2bs(acc);
}

// ---------------- per-query: gamma -> xq -> qvec ; h_l bands ----------------
__global__ __launch_bounds__(256) void k_query(const u16* canon, const float* xraw,
      const unsigned* flag, const u16* WT, u16* qvecB, u16* hlB){
  int t = threadIdx.x, q0 = blockIdx.x * 16;
  const u16* q_b = canon + C_QB;
  const u16* bw_b= canon + C_BWB;
  int lane = t & 63, wv = t >> 6, l15 = lane & 15, q4 = lane >> 4;
  __shared__ __align__(16) u16 g[16*136];
  __shared__ __align__(16) u16 xql[16*520];
  __shared__ float cco[32];
  __shared__ float omg[32];
  for (int e = t; e < 16*136; e += 256) g[e] = 0;
  for (int e = t; e < 16*520; e += 256) xql[e] = 0;
  if (t < 32) cco[t] = (*flag) ? xraw[q0*2 + t] : bs2f(canon[C_X + q0*2 + t]);
  if (t < 32) omg[t] = (float)pow(10.0, 1.0 + t * ((2.1072099696478683 - 1.0)/31.0));
  __syncthreads();
  for (int i = 0; i < 8; i++){
    int id = i*256 + t, qi = id >> 7, f = id & 127;
    int d = f >> 6, r = f & 63, fi = r & 31;
    float arg = PI_F * cco[qi*2 + d] * omg[fi];
    g[qi*136 + f] = f2bs((r < 32) ? sinf(arg) : cosf(arg));
  }
  __syncthreads();
  { // xq = relu(g @ q_W + q_b) -> xql
    const u16* Bm = WT + QWT_OFF;
    for (int nt = 0; nt < 8; nt++){
      f32x4 acc = {0.f,0.f,0.f,0.f};
      int c = wv*128 + nt*16 + l15;
      for (int ks = 0; ks < 4; ks++){
        bf16x8 a  = ld8(g + l15*136 + ks*32 + q4*8);
        bf16x8 bb = ld8(Bm + (size_t)c*128 + ks*32 + q4*8);
        acc = mfma16(a, bb, acc);
      }
      float qb = bs2f(q_b[c]);
      for (int rg = 0; rg < 4; rg++){
        int row = q4*4 + rg;
        xql[row*520 + c] = f2bs(fmaxf(acc[rg] + qb, 0.f));
      }
    }
  }
  __syncthreads();
  { // qvec = xq @ Wq -> stage in g -> coalesced store
    const u16* Bm = WT + WQT_OFF;
    for (int nh = 0; nh < 2; nh++){
      f32x4 acc = {0.f,0.f,0.f,0.f};
      int c = wv*32 + nh*16 + l15;
      for (int ks = 0; ks < 16; ks++){
        bf16x8 a  = ld8(xql + l15*520 + ks*32 + q4*8);
        bf16x8 bb = ld8(Bm + (size_t)c*512 + ks*32 + q4*8);
        acc = mfma16(a, bb, acc);
      }
      for (int rg = 0; rg < 4; rg++)
        g[(q4*4 + rg)*128 + c] = f2bs(acc[rg]);
    }
    __syncthreads();
    {
      int rr = t >> 4, cc = (t & 15)*8;
      *(u16x8*)(qvecB + (size_t)(q0 + rr)*128 + cc) = *(const u16x8*)(g + rr*128 + cc);
    }
  }
  const double LG[3] = {1.2041199826559248, 1.8061799739838869, 2.4082399653118496};
  for (int ib = 0; ib < 3; ib++){
    __syncthreads();
    if (t < 32) omg[t] = (float)pow(10.0, 1.0 + t * ((LG[ib] - 1.0)/31.0));
    __syncthreads();
    for (int i = 0; i < 8; i++){
      int id = i*256 + t, qi = id >> 7, f = id & 127;
      int d = f >> 6, r = f & 63, fi = r & 31;
      float arg = PI_F * cco[qi*2 + d] * omg[fi];
      g[qi*136 + f] = f2bs((r < 32) ? sinf(arg) : cosf(arg));
    }
    __syncthreads();
    const u16* Bm = WT + BWT_OFF + ib*65536;
    for (int nt = 0; nt < 8; nt++){
      f32x4 acc = {0.f,0.f,0.f,0.f};
      int c = wv*128 + nt*16 + l15;
      for (int ks = 0; ks < 4; ks++){
        bf16x8 a  = ld8(g + l15*136 + ks*32 + q4*8);
        bf16x8 bb = ld8(Bm + (size_t)c*128 + ks*32 + q4*8);
        acc = mfma16(a, bb, acc);
      }
      float bias = bs2f(bw_b[ib*512 + c]);
      for (int rg = 0; rg < 4; rg++)
        xql[(q4*4 + rg)*520 + c] = f2bs(fmaxf(acc[rg] + bias, 0.f));
    }
    __syncthreads();
    for (int it = 0; it < 4; it++){
      int rr = it*4 + (t >> 6), cc = (t & 63)*8;
      *(u16x8*)(hlB + ((size_t)ib*HWQ + q0 + rr)*512 + cc) = *(const u16x8*)(xql + rr*520 + cc);
    }
  }
}

// ---------------- attention + mod projection (f32 softmax, staged store) ----------------
__global__ __launch_bounds__(256) void k_attn(const u16* canon, const float* xraw,
      const unsigned* flag, const u16* qvecB, const u16* kpart, const u16* vT,
      const u16* WT, u16* modB){
  int t = threadIdx.x;
  int b = blockIdx.x & 7, qt = blockIdx.x >> 3, q0 = qt*32;
  const u16* bo = canon + C_BO;
  int lane = t & 63, wv = t >> 6, l15 = lane & 15, q4 = lane >> 4;
  __shared__ __align__(16) u16 ql[32*136];
  __shared__ __align__(16) u16 pl[32*264];
  __shared__ __align__(16) float pf[32*264];
  __shared__ __align__(16) u16 ot[32*136];
  __shared__ float tqs[32];
  __shared__ float red[256];
  __shared__ float rst[32];
  for (int e = t; e < 32*136; e += 256){ ql[e] = 0; ot[e] = 0; }
  for (int e = t; e < 32*264; e += 256) pl[e] = 0;
  __syncthreads();
  for (int i = 0; i < 16; i++){
    int id = i*256 + t, qi = id >> 7, c = id & 127;
    ql[qi*136 + c] = qvecB[(size_t)(q0 + qi)*128 + c];
  }
  if (t < 32){
    float c0, c1;
    if (*flag){ c0 = xraw[(q0+t)*2]; c1 = xraw[(q0+t)*2 + 1]; }
    else { c0 = bs2f(canon[C_X + (q0+t)*2]); c1 = bs2f(canon[C_X + (q0+t)*2 + 1]); }
    int rr = (int)(c0*16.f), cc = (int)(c1*16.f);
    tqs[t] = (float)(rr*16 + cc) * (1.f/256.f);
  }
  __syncthreads();
  for (int h = 0; h < 2; h++){
    f32x4 sac[2][4];
    for (int mt = 0; mt < 2; mt++) for (int nt = 0; nt < 4; nt++) sac[mt][nt] = (f32x4){0.f,0.f,0.f,0.f};
    const u16* kb = kpart + (size_t)b*256*128 + h*64;
    for (int ks = 0; ks < 2; ks++){
      bf16x8 a0 = ld8(ql + l15*136 + h*64 + ks*32 + q4*8);
      bf16x8 a1 = ld8(ql + (16+l15)*136 + h*64 + ks*32 + q4*8);
      for (int nt = 0; nt < 4; nt++){
        int kk = wv*64 + nt*16 + l15;
        bf16x8 bb = ld8(kb + (size_t)kk*128 + ks*32 + q4*8);
        sac[0][nt] = mfma16(a0, bb, sac[0][nt]);
        sac[1][nt] = mfma16(a1, bb, sac[1][nt]);
      }
    }
    for (int mt = 0; mt < 2; mt++) for (int nt = 0; nt < 4; nt++){
      int kk = wv*64 + nt*16 + l15;
      float pos = ((float)kk + 0.5f) * (1.f/256.f);
      for (int rg = 0; rg < 4; rg++){
        int row = mt*16 + q4*4 + rg;
        float dd = tqs[row] - pos;
        pf[row*264 + kk] = sac[mt][nt][rg]*0.125f - 10.f*dd*dd;
      }
    }
    __syncthreads();
    {
      int r = t >> 3, i = t & 7;
      float* pr = pf + r*264 + i*32;
      u16* po = pl + r*264 + i*32;
      float m = -1e30f;
      for (int j = 0; j < 32; j++) m = fmaxf(m, pr[j]);
      red[t] = m;
      __syncthreads();
      if (t < 32){ float mm = red[t*8];
        for (int j = 1; j < 8; j++) mm = fmaxf(mm, red[t*8+j]);
        rst[t] = mm; }
      __syncthreads();
      float mm = rst[r], sum = 0.f;
      for (int j = 0; j < 32; j++){ float e = expf(pr[j] - mm); pr[j] = e; sum += e; }
      red[t] = sum;
      __syncthreads();
      if (t < 32){ float ss = 0.f;
        for (int j = 0; j < 8; j++) ss += red[t*8+j];
        rst[t] = 1.f/ss; }
      __syncthreads();
      float inv = rst[r];
      for (int j = 0; j < 32; j++) po[j] = f2bs(pr[j] * inv);
    }
    __syncthreads();
    f32x4 oac[2] = {(f32x4){0.f,0.f,0.f,0.f}, (f32x4){0.f,0.f,0.f,0.f}};
    const u16* vb = vT + ((size_t)b*128 + h*64)*256;
    int dl = wv*16 + l15;
    for (int ks = 0; ks < 8; ks++){
      bf16x8 a0 = ld8(pl + l15*264 + ks*32 + q4*8);
      bf16x8 a1 = ld8(pl + (16+l15)*264 + ks*32 + q4*8);
      bf16x8 bb = ld8(vb + (size_t)dl*256 + ks*32 + q4*8);
      oac[0] = mfma16(a0, bb, oac[0]);
      oac[1] = mfma16(a1, bb, oac[1]);
    }
    for (int mt = 0; mt < 2; mt++) for (int rg = 0; rg < 4; rg++){
      int row = mt*16 + q4*4 + rg;
      ot[row*136 + h*64 + dl] = f2bs(oac[mt][rg]);
    }
    __syncthreads();
  }
  // mod = ot @ Wo + bo : stage into pf (as u16) then coalesced store
  u16* stg = (u16*)pf;
  const u16* wob = WT + WOT_OFF;
  for (int nt = 0; nt < 8; nt++){
    f32x4 mac[2] = {(f32x4){0.f,0.f,0.f,0.f}, (f32x4){0.f,0.f,0.f,0.f}};
    int c = wv*128 + nt*16 + l15;
    for (int ks = 0; ks < 4; ks++){
      bf16x8 a0 = ld8(ot + l15*136 + ks*32 + q4*8);
      bf16x8 a1 = ld8(ot + (16+l15)*136 + ks*32 + q4*8);
      bf16x8 bb = ld8(wob + (size_t)c*128 + ks*32 + q4*8);
      mac[0] = mfma16(a0, bb, mac[0]);
      mac[1] = mfma16(a1, bb, mac[1]);
    }
    float bv = bs2f(bo[c]);
    for (int mt = 0; mt < 2; mt++) for (int rg = 0; rg < 4; rg++){
      int row = mt*16 + q4*4 + rg;
      stg[row*512 + c] = f2bs(mac[mt][rg] + bv);
    }
  }
  __syncthreads();
  for (int it = 0; it < 8; it++){
    int rr = it*4 + (t >> 6), cc = (t & 63)*8;
    *(u16x8*)(modB + ((size_t)(q0+rr)*8 + b)*512 + cc) = *(const u16x8*)(stg + rr*512 + cc);
  }
}

// ================= k_bands2: 32-row blocks, B direct from L2, X in LDS =================
// Macros (not functions) to avoid passing MFMA accumulator arrays by reference — ICE workaround.
#define GEMM32_G(Aptr, Bw)                                                        \
  { for (int mt = 0; mt < 2; mt++) for (int nt = 0; nt < 8; nt++)                 \
      acc[mt][nt] = (f32x4){0.f,0.f,0.f,0.f};                                     \
    for (int ks = 0; ks < 16; ks++){                                              \
      bf16x8 a0 = ld8((Aptr) + (size_t)l15*512 + ks*32 + q4*8);                   \
      bf16x8 a1 = ld8((Aptr) + (size_t)(16 + l15)*512 + ks*32 + q4*8);            \
      for (int nt = 0; nt < 8; nt++){                                             \
        bf16x8 bb = ld8((Bw) + (size_t)(w*128 + nt*16 + l15)*512 + ks*32 + q4*8); \
        acc[0][nt] = mfma16(a0, bb, acc[0][nt]);                                  \
        acc[1][nt] = mfma16(a1, bb, acc[1][nt]);                                  \
      } } }

#define GEMM32_L(Aptr, Bw)                                                        \
  { for (int mt = 0; mt < 2; mt++) for (int nt = 0; nt < 8; nt++)                 \
      acc[mt][nt] = (f32x4){0.f,0.f,0.f,0.f};                                     \
    for (int ks = 0; ks < 16; ks++){                                              \
      bf16x8 a0 = ld8((Aptr) + l15*520 + ks*32 + q4*8);                           \
      bf16x8 a1 = ld8((Aptr) + (16 + l15)*520 + ks*32 + q4*8);                    \
      for (int nt = 0; nt < 8; nt++){                                             \
        bf16x8 bb = ld8((Bw) + (size_t)(w*128 + nt*16 + l15)*512 + ks*32 + q4*8); \
        acc[0][nt] = mfma16(a0, bb, acc[0][nt]);                                  \
        acc[1][nt] = mfma16(a1, bb, acc[1][nt]);                                  \
      } } }

__global__ __launch_bounds__(256, 2) void k_bands2(const u16* canon, const u16* modB,
      const u16* WT, const u16* hlB, const unsigned* flag, void* outv){
  int t = threadIdx.x, rgp = blockIdx.x;
  int lane = t & 63, w = t >> 6, l15 = lane & 15, q4 = lane >> 4;
  __shared__ __align__(16) u16 xa[32*520];
  __shared__ __align__(16) u16 xb[32*520];
  __shared__ float projacc[384];   // [w][row][o] = ((w*32)+row)*3+o
  for (int e = t; e < 384; e += 256) projacc[e] = 0.f;
  __syncthreads();
  const u16* Agl = modB + (size_t)rgp*32*512;
  const u16* hl0 = hlB;
  const u16* hl1 = hlB + (size_t)HWQ*512;
  const u16* hl2 = hlB + (size_t)2*HWQ*512;
  int qbase = rgp*4;
  f32x4 acc[2][8];

  // ---- g1: X1 = relu(mod@W0 + b0 + hl0) -> xa ; proj0 ----
  GEMM32_G(Agl, WT + MODT_OFF);
  {
    float ow[8][3], bias[8];
    for (int nt = 0; nt < 8; nt++){
      int c = w*128 + nt*16 + l15;
      bias[nt] = bs2f(canon[C_MODB + c]);
      for (int o = 0; o < 3; o++) ow[nt][o] = bs2f(canon[C_OUTW + c*3 + o]);
    }
    for (int mt = 0; mt < 2; mt++) for (int rg = 0; rg < 4; rg++){
      int row = mt*16 + q4*4 + rg;
      int q = qbase + (row >> 3);
      float p0 = 0.f, p1 = 0.f, p2 = 0.f;
      for (int nt = 0; nt < 8; nt++){
        int c = w*128 + nt*16 + l15;
        float v = acc[mt][nt][rg] + bias[nt] + bs2f(hl0[(size_t)q*512 + c]);
        v = fmaxf(v, 0.f);
        xa[row*520 + c] = f2bs(v);
        p0 += v*ow[nt][0]; p1 += v*ow[nt][1]; p2 += v*ow[nt][2];
      }
      for (int m = 1; m < 16; m <<= 1){
        p0 += __shfl_xor(p0, m, 64); p1 += __shfl_xor(p1, m, 64); p2 += __shfl_xor(p2, m, 64);
      }
      if (l15 == 0){
        projacc[(w*32 + row)*3 + 0] += p0;
        projacc[(w*32 + row)*3 + 1] += p1;
        projacc[(w*32 + row)*3 + 2] += p2;
      }
    }
  }
  __syncthreads();

  // ---- g2: X2 = relu(mod@W1 + b1 + hl1) + X1 -> xb ----
  GEMM32_G(Agl, WT + MODT_OFF + 262144);
  {
    float bias[8];
    for (int nt = 0; nt < 8; nt++) bias[nt] = bs2f(canon[C_MODB + 512 + w*128 + nt*16 + l15]);
    for (int mt = 0; mt < 2; mt++) for (int rg = 0; rg < 4; rg++){
      int row = mt*16 + q4*4 + rg;
      int q = qbase + (row >> 3);
      for (int nt = 0; nt < 8; nt++){
        int c = w*128 + nt*16 + l15;
        float v = acc[mt][nt][rg] + bias[nt] + bs2f(hl1[(size_t)q*512 + c]);
        v = fmaxf(v, 0.f) + bs2f(xa[row*520 + c]);
        xb[row*520 + c] = f2bs(v);
      }
    }
  }
  __syncthreads();

  // ---- g3: X3 = relu(X2@hv0 + hvb0) -> xa ; proj1 ----
  GEMM32_L(xb, WT + HVT_OFF);
  {
    float ow[8][3], bias[8];
    for (int nt = 0; nt < 8; nt++){
      int c = w*128 + nt*16 + l15;
      bias[nt] = bs2f(canon[C_HVB + c]);
      for (int o = 0; o < 3; o++) ow[nt][o] = bs2f(canon[C_OUTW + 1536 + c*3 + o]);
    }
    for (int mt = 0; mt < 2; mt++) for (int rg = 0; rg < 4; rg++){
      int row = mt*16 + q4*4 + rg;
      float p0 = 0.f, p1 = 0.f, p2 = 0.f;
      for (int nt = 0; nt < 8; nt++){
        int c = w*128 + nt*16 + l15;
        float v = fmaxf(acc[mt][nt][rg] + bias[nt], 0.f);
        xa[row*520 + c] = f2bs(v);
        p0 += v*ow[nt][0]; p1 += v*ow[nt][1]; p2 += v*ow[nt][2];
      }
      for (int m = 1; m < 16; m <<= 1){
        p0 += __shfl_xor(p0, m, 64); p1 += __shfl_xor(p1, m, 64); p2 += __shfl_xor(p2, m, 64);
      }
      if (l15 == 0){
        projacc[(w*32 + row)*3 + 0] += p0;
        projacc[(w*32 + row)*3 + 1] += p1;
        projacc[(w*32 + row)*3 + 2] += p2;
      }
    }
  }
  __syncthreads();

  // ---- g4: X4 = relu(mod@W2 + b2 + hl2) + X3 -> xb ----
  GEMM32_G(Agl, WT + MODT_OFF + 524288);
  {
    float bias[8];
    for (int nt = 0; nt < 8; nt++) bias[nt] = bs2f(canon[C_MODB + 1024 + w*128 + nt*16 + l15]);
    for (int mt = 0; mt < 2; mt++) for (int rg = 0; rg < 4; rg++){
      int row = mt*16 + q4*4 + rg;
      int q = qbase + (row >> 3);
      for (int nt = 0; nt < 8; nt++){
        int c = w*128 + nt*16 + l15;
        float v = acc[mt][nt][rg] + bias[nt] + bs2f(hl2[(size_t)q*512 + c]);
        v = fmaxf(v, 0.f) + bs2f(xa[row*520 + c]);
        xb[row*520 + c] = f2bs(v);
      }
    }
  }
  __syncthreads();

  // ---- g5: X5 = relu(X4@hv1 + hvb1) ; proj2 only ----
  GEMM32_L(xb, WT + HVT_OFF + 262144);
  {
    float ow[8][3], bias[8];
    for (int nt = 0; nt < 8; nt++){
      int c = w*128 + nt*16 + l15;
      bias[nt] = bs2f(canon[C_HVB + 512 + c]);
      for (int o = 0; o < 3; o++) ow[nt][o] = bs2f(canon[C_OUTW + 3072 + c*3 + o]);
    }
    for (int mt = 0; mt < 2; mt++) for (int rg = 0; rg < 4; rg++){
      int row = mt*16 + q4*4 + rg;
      float p0 = 0.f, p1 = 0.f, p2 = 0.f;
      for (int nt = 0; nt < 8; nt++){
        float v = fmaxf(acc[mt][nt][rg] + bias[nt], 0.f);
        p0 += v*ow[nt][0]; p1 += v*ow[nt][1]; p2 += v*ow[nt][2];
      }
      for (int m = 1; m < 16; m <<= 1){
        p0 += __shfl_xor(p0, m, 64); p1 += __shfl_xor(p1, m, 64); p2 += __shfl_xor(p2, m, 64);
      }
      if (l15 == 0){
        projacc[(w*32 + row)*3 + 0] += p0;
        projacc[(w*32 + row)*3 + 1] += p1;
        projacc[(w*32 + row)*3 + 2] += p2;
      }
    }
  }
  __syncthreads();

  // ---- final: reduce proj over waves, add biases, store ----
  if (t < 96){
    int row = t / 3, o = t - (t/3)*3;
    float s = bs2f(canon[C_OUTB + o]) + bs2f(canon[C_OUTB + 3 + o]) + bs2f(canon[C_OUTB + 6 + o]);
    for (int w2 = 0; w2 < 4; w2++) s += projacc[(w2*32 + row)*3 + o];
    int gr = rgp*32 + row;
    int b = gr & 7, q = gr >> 3;
    size_t idx = ((size_t)b*HWQ + q)*3 + o;
    if (*flag) ((float*)outv)[idx] = s;
    else       ((u16*)outv)[idx]   = f2bs(s);
  }
}

extern "C" void kernel_launch(void* const* d_in, const int* in_sizes, int n_in,
                              void* d_out, int out_size, void* d_ws, size_t ws_size,
                              hipStream_t stream){
  (void)in_sizes; (void)n_in; (void)out_size;

  u16* wsp   = (u16*)d_ws;
  unsigned* flag = (unsigned*)wsp;
  u16* canon = wsp + 8;
  u16* WT    = canon + CANON_PAD;
  u16* kpart = WT + 1703936;
  u16* vT    = kpart + 262144;
  u16* qvecB = vT + 262144;
  u16* hlB   = qvecB + 2097152;
  u16* modB  = hlB + 25165824;
  if (ws_size < 199773250ULL) return;

  SrcPtrs sp;
  for (int i = 0; i < 16; i++) sp.p[i] = d_in[i];
  const float* xraw = (const float*)d_in[0];

  k_detect <<<1, 256, 0, stream>>>((const u16*)d_in[3], flag);
  k_convert<<<(C_TOTAL + 255)/256, 256, 0, stream>>>(sp, flag, canon);
  k_tr     <<<1664, 256, 0, stream>>>(canon, WT);
  k_kv     <<<2048, 256, 0, stream>>>(canon, kpart, vT);
  k_query  <<<1024, 256, 0, stream>>>(canon, xraw, flag, WT, qvecB, hlB);
  k_attn   <<<4096, 256, 0, stream>>>(canon, xraw, flag, qvecB, kpart, vT, WT, modB);
  k_bands2 <<<4096, 256, 0, stream>>>(canon, modB, WT, hlB, flag, d_out);
}

// Round 11
// 1754.973 us; speedup vs baseline: 3.4027x; 1.0115x over previous
//
#include <hip/hip_runtime.h>
#include <math.h>

typedef unsigned short u16;
typedef unsigned int uint;
typedef __bf16 bf16x8 __attribute__((ext_vector_type(8)));
typedef unsigned short u16x8 __attribute__((ext_vector_type(8)));
typedef float f32x4 __attribute__((ext_vector_type(4)));

#define HWQ 16384
#define PI_F 3.14159265358979323846f

// canonical (bf16) input offsets inside ws
#define C_X     0
#define C_TOK   262144
#define C_QW    1310720
#define C_QB    1376256
#define C_WQ    1376768
#define C_WKV   1442304
#define C_WO    1704448
#define C_BO    1769984
#define C_BWW   1770496
#define C_BWB   1967104
#define C_MODW  1968640
#define C_MODB  2755072
#define C_HVW   2756608
#define C_HVB   3280896
#define C_OUTW  3281920
#define C_OUTB  3286528
#define C_TOTAL 3286537
#define CANON_PAD 3286544

// WT (transposed weights) element offsets (relative to WT base)
#define QWT_OFF  0
#define WQT_OFF  65536
#define WOT_OFF  131072
#define BWT_OFF  196608
#define MODT_OFF 393216
#define HVT_OFF  1179648

struct SrcPtrs { const void* p[16]; };

__device__ __forceinline__ float bs2f(u16 u){
  unsigned v = ((unsigned)u) << 16; float f; __builtin_memcpy(&f, &v, 4); return f;
}
__device__ __forceinline__ u16 f2bs(float f){
  unsigned v; __builtin_memcpy(&v, &f, 4);
  v = (v + 0x7fffu + ((v >> 16) & 1u)) >> 16;
  return (u16)v;
}
__device__ __forceinline__ f32x4 mfma16(bf16x8 a, bf16x8 b, f32x4 c){
  return __builtin_amdgcn_mfma_f32_16x16x32_bf16(a, b, c, 0, 0, 0);
}
__device__ __forceinline__ bf16x8 ld8(const u16* p){ return *(const bf16x8*)p; }

// ---------------- dtype detect ----------------
__global__ void k_detect(const u16* qb_raw, unsigned* flag){
  __shared__ int cnt[256];
  int t = threadIdx.x;
  u16 u = qb_raw[2*t];
  int e = (u >> 7) & 0xFF;
  cnt[t] = (e >= 126) ? 1 : 0;
  __syncthreads();
  for (int s = 128; s > 0; s >>= 1){
    if (t < s) cnt[t] += cnt[t + s];
    __syncthreads();
  }
  if (t == 0) *flag = (cnt[0] >= 16) ? 1u : 0u;
}

// ---------------- convert inputs to canonical bf16 ----------------
__global__ __launch_bounds__(256) void k_convert(SrcPtrs sp, const unsigned* flag, u16* canon){
  const int offs[17] = {C_X,C_TOK,C_QW,C_QB,C_WQ,C_WKV,C_WO,C_BO,C_BWW,C_BWB,
                        C_MODW,C_MODB,C_HVW,C_HVB,C_OUTW,C_OUTB,C_TOTAL};
  int e = blockIdx.x * 256 + threadIdx.x;
  if (e >= C_TOTAL) return;
  int seg = 0;
  for (int i = 1; i < 16; i++) if (e >= offs[i]) seg = i;
  int local = e - offs[seg];
  if (*flag) canon[e] = f2bs(((const float*)sp.p[seg])[local]);
  else       canon[e] = ((const u16*)sp.p[seg])[local];
}

// ---------------- weight transpose ----------------
__global__ __launch_bounds__(256) void k_tr(const u16* canon, u16* WT){
  __shared__ u16 tile[32][33];
  int bid = blockIdx.x, t = threadIdx.x;
  const u16* src; u16* dst; int K, N, tl;
  if (bid < 384){
    int m = bid >> 6; tl = bid & 63;
    if (m == 0){ src = canon + C_QW;  dst = WT + QWT_OFF; K = 128; N = 512; }
    else if (m == 1){ src = canon + C_WQ; dst = WT + WQT_OFF; K = 512; N = 128; }
    else if (m == 2){ src = canon + C_WO; dst = WT + WOT_OFF; K = 128; N = 512; }
    else { src = canon + C_BWW + (m-3)*65536; dst = WT + BWT_OFF + (m-3)*65536; K = 128; N = 512; }
  } else if (bid < 1152){
    int m = (bid - 384) >> 8; tl = (bid - 384) & 255;
    src = canon + C_MODW + m*262144; dst = WT + MODT_OFF + m*262144; K = 512; N = 512;
  } else {
    int m = (bid - 1152) >> 8; tl = (bid - 1152) & 255;
    src = canon + C_HVW + m*262144; dst = WT + HVT_OFF + m*262144; K = 512; N = 512;
  }
  int kt = K >> 5;
  int k0 = (tl % kt) * 32, n0 = (tl / kt) * 32;
  int tx = t & 31, ty = t >> 5;
  for (int r = 0; r < 4; r++)
    tile[ty + r*8][tx] = src[(size_t)(k0 + ty + r*8) * N + n0 + tx];
  __syncthreads();
  for (int r = 0; r < 4; r++)
    dst[(size_t)(n0 + ty + r*8) * K + k0 + tx] = tile[tx][ty + r*8];
}

// ---------------- kv = tokens @ Wkv ----------------
__global__ __launch_bounds__(256) void k_kv(const u16* canon, u16* kpart, u16* vT){
  int b = blockIdx.x >> 8, kk = blockIdx.x & 255, t = threadIdx.x;
  const u16* tok = canon + C_TOK;
  const u16* Wkv = canon + C_WKV;
  __shared__ float tk[512];
  const u16* tr = tok + ((size_t)(b*256 + kk)) * 512;
  tk[t] = bs2f(tr[t]); tk[t+256] = bs2f(tr[t+256]);
  __syncthreads();
  float acc = 0.f;
  for (int k = 0; k < 512; k++) acc += tk[k] * bs2f(Wkv[k*256 + t]);
  if (t < 128) kpart[((size_t)(b*256 + kk))*128 + t] = f2bs(acc);
  else vT[((size_t)b*128 + (t-128))*256 + kk] = f2bs(acc);
}

// ---------------- per-query: gamma -> xq -> qvec ; h_l bands ----------------
__global__ __launch_bounds__(256) void k_query(const u16* canon, const float* xraw,
      const unsigned* flag, const u16* WT, u16* qvecB, u16* hlB){
  int t = threadIdx.x, q0 = blockIdx.x * 16;
  const u16* q_b = canon + C_QB;
  const u16* bw_b= canon + C_BWB;
  int lane = t & 63, wv = t >> 6, l15 = lane & 15, q4 = lane >> 4;
  __shared__ __align__(16) u16 g[16*136];
  __shared__ __align__(16) u16 xql[16*520];
  __shared__ float cco[32];
  __shared__ float omg[32];
  for (int e = t; e < 16*136; e += 256) g[e] = 0;
  for (int e = t; e < 16*520; e += 256) xql[e] = 0;
  if (t < 32) cco[t] = (*flag) ? xraw[q0*2 + t] : bs2f(canon[C_X + q0*2 + t]);
  if (t < 32) omg[t] = (float)pow(10.0, 1.0 + t * ((2.1072099696478683 - 1.0)/31.0));
  __syncthreads();
  for (int i = 0; i < 8; i++){
    int id = i*256 + t, qi = id >> 7, f = id & 127;
    int d = f >> 6, r = f & 63, fi = r & 31;
    float arg = PI_F * cco[qi*2 + d] * omg[fi];
    g[qi*136 + f] = f2bs((r < 32) ? sinf(arg) : cosf(arg));
  }
  __syncthreads();
  { // xq = relu(g @ q_W + q_b) -> xql
    const u16* Bm = WT + QWT_OFF;
    for (int nt = 0; nt < 8; nt++){
      f32x4 acc = {0.f,0.f,0.f,0.f};
      int c = wv*128 + nt*16 + l15;
      for (int ks = 0; ks < 4; ks++){
        bf16x8 a  = ld8(g + l15*136 + ks*32 + q4*8);
        bf16x8 bb = ld8(Bm + (size_t)c*128 + ks*32 + q4*8);
        acc = mfma16(a, bb, acc);
      }
      float qb = bs2f(q_b[c]);
      for (int rg = 0; rg < 4; rg++){
        int row = q4*4 + rg;
        xql[row*520 + c] = f2bs(fmaxf(acc[rg] + qb, 0.f));
      }
    }
  }
  __syncthreads();
  { // qvec = xq @ Wq -> stage in g -> coalesced store
    const u16* Bm = WT + WQT_OFF;
    for (int nh = 0; nh < 2; nh++){
      f32x4 acc = {0.f,0.f,0.f,0.f};
      int c = wv*32 + nh*16 + l15;
      for (int ks = 0; ks < 16; ks++){
        bf16x8 a  = ld8(xql + l15*520 + ks*32 + q4*8);
        bf16x8 bb = ld8(Bm + (size_t)c*512 + ks*32 + q4*8);
        acc = mfma16(a, bb, acc);
      }
      for (int rg = 0; rg < 4; rg++)
        g[(q4*4 + rg)*128 + c] = f2bs(acc[rg]);
    }
    __syncthreads();
    {
      int rr = t >> 4, cc = (t & 15)*8;
      *(u16x8*)(qvecB + (size_t)(q0 + rr)*128 + cc) = *(const u16x8*)(g + rr*128 + cc);
    }
  }
  const double LG[3] = {1.2041199826559248, 1.8061799739838869, 2.4082399653118496};
  for (int ib = 0; ib < 3; ib++){
    __syncthreads();
    if (t < 32) omg[t] = (float)pow(10.0, 1.0 + t * ((LG[ib] - 1.0)/31.0));
    __syncthreads();
    for (int i = 0; i < 8; i++){
      int id = i*256 + t, qi = id >> 7, f = id & 127;
      int d = f >> 6, r = f & 63, fi = r & 31;
      float arg = PI_F * cco[qi*2 + d] * omg[fi];
      g[qi*136 + f] = f2bs((r < 32) ? sinf(arg) : cosf(arg));
    }
    __syncthreads();
    const u16* Bm = WT + BWT_OFF + ib*65536;
    for (int nt = 0; nt < 8; nt++){
      f32x4 acc = {0.f,0.f,0.f,0.f};
      int c = wv*128 + nt*16 + l15;
      for (int ks = 0; ks < 4; ks++){
        bf16x8 a  = ld8(g + l15*136 + ks*32 + q4*8);
        bf16x8 bb = ld8(Bm + (size_t)c*128 + ks*32 + q4*8);
        acc = mfma16(a, bb, acc);
      }
      float bias = bs2f(bw_b[ib*512 + c]);
      for (int rg = 0; rg < 4; rg++)
        xql[(q4*4 + rg)*520 + c] = f2bs(fmaxf(acc[rg] + bias, 0.f));
    }
    __syncthreads();
    for (int it = 0; it < 4; it++){
      int rr = it*4 + (t >> 6), cc = (t & 63)*8;
      *(u16x8*)(hlB + ((size_t)ib*HWQ + q0 + rr)*512 + cc) = *(const u16x8*)(xql + rr*520 + cc);
    }
  }
}

// ---------------- attention + mod projection (f32 softmax, staged store) ----------------
__global__ __launch_bounds__(256) void k_attn(const u16* canon, const float* xraw,
      const unsigned* flag, const u16* qvecB, const u16* kpart, const u16* vT,
      const u16* WT, u16* modB){
  int t = threadIdx.x;
  int b = blockIdx.x & 7, qt = blockIdx.x >> 3, q0 = qt*32;
  const u16* bo = canon + C_BO;
  int lane = t & 63, wv = t >> 6, l15 = lane & 15, q4 = lane >> 4;
  __shared__ __align__(16) u16 ql[32*136];
  __shared__ __align__(16) u16 pl[32*264];
  __shared__ __align__(16) float pf[32*264];
  __shared__ __align__(16) u16 ot[32*136];
  __shared__ float tqs[32];
  __shared__ float red[256];
  __shared__ float rst[32];
  for (int e = t; e < 32*136; e += 256){ ql[e] = 0; ot[e] = 0; }
  for (int e = t; e < 32*264; e += 256) pl[e] = 0;
  __syncthreads();
  for (int i = 0; i < 16; i++){
    int id = i*256 + t, qi = id >> 7, c = id & 127;
    ql[qi*136 + c] = qvecB[(size_t)(q0 + qi)*128 + c];
  }
  if (t < 32){
    float c0, c1;
    if (*flag){ c0 = xraw[(q0+t)*2]; c1 = xraw[(q0+t)*2 + 1]; }
    else { c0 = bs2f(canon[C_X + (q0+t)*2]); c1 = bs2f(canon[C_X + (q0+t)*2 + 1]); }
    int rr = (int)(c0*16.f), cc = (int)(c1*16.f);
    tqs[t] = (float)(rr*16 + cc) * (1.f/256.f);
  }
  __syncthreads();
  for (int h = 0; h < 2; h++){
    f32x4 sac[2][4];
    for (int mt = 0; mt < 2; mt++) for (int nt = 0; nt < 4; nt++) sac[mt][nt] = (f32x4){0.f,0.f,0.f,0.f};
    const u16* kb = kpart + (size_t)b*256*128 + h*64;
    for (int ks = 0; ks < 2; ks++){
      bf16x8 a0 = ld8(ql + l15*136 + h*64 + ks*32 + q4*8);
      bf16x8 a1 = ld8(ql + (16+l15)*136 + h*64 + ks*32 + q4*8);
      for (int nt = 0; nt < 4; nt++){
        int kk = wv*64 + nt*16 + l15;
        bf16x8 bb = ld8(kb + (size_t)kk*128 + ks*32 + q4*8);
        sac[0][nt] = mfma16(a0, bb, sac[0][nt]);
        sac[1][nt] = mfma16(a1, bb, sac[1][nt]);
      }
    }
    for (int mt = 0; mt < 2; mt++) for (int nt = 0; nt < 4; nt++){
      int kk = wv*64 + nt*16 + l15;
      float pos = ((float)kk + 0.5f) * (1.f/256.f);
      for (int rg = 0; rg < 4; rg++){
        int row = mt*16 + q4*4 + rg;
        float dd = tqs[row] - pos;
        pf[row*264 + kk] = sac[mt][nt][rg]*0.125f - 10.f*dd*dd;
      }
    }
    __syncthreads();
    {
      int r = t >> 3, i = t & 7;
      float* pr = pf + r*264 + i*32;
      u16* po = pl + r*264 + i*32;
      float m = -1e30f;
      for (int j = 0; j < 32; j++) m = fmaxf(m, pr[j]);
      red[t] = m;
      __syncthreads();
      if (t < 32){ float mm = red[t*8];
        for (int j = 1; j < 8; j++) mm = fmaxf(mm, red[t*8+j]);
        rst[t] = mm; }
      __syncthreads();
      float mm = rst[r], sum = 0.f;
      for (int j = 0; j < 32; j++){ float e = expf(pr[j] - mm); pr[j] = e; sum += e; }
      red[t] = sum;
      __syncthreads();
      if (t < 32){ float ss = 0.f;
        for (int j = 0; j < 8; j++) ss += red[t*8+j];
        rst[t] = 1.f/ss; }
      __syncthreads();
      float inv = rst[r];
      for (int j = 0; j < 32; j++) po[j] = f2bs(pr[j] * inv);
    }
    __syncthreads();
    f32x4 oac[2] = {(f32x4){0.f,0.f,0.f,0.f}, (f32x4){0.f,0.f,0.f,0.f}};
    const u16* vb = vT + ((size_t)b*128 + h*64)*256;
    int dl = wv*16 + l15;
    for (int ks = 0; ks < 8; ks++){
      bf16x8 a0 = ld8(pl + l15*264 + ks*32 + q4*8);
      bf16x8 a1 = ld8(pl + (16+l15)*264 + ks*32 + q4*8);
      bf16x8 bb = ld8(vb + (size_t)dl*256 + ks*32 + q4*8);
      oac[0] = mfma16(a0, bb, oac[0]);
      oac[1] = mfma16(a1, bb, oac[1]);
    }
    for (int mt = 0; mt < 2; mt++) for (int rg = 0; rg < 4; rg++){
      int row = mt*16 + q4*4 + rg;
      ot[row*136 + h*64 + dl] = f2bs(oac[mt][rg]);
    }
    __syncthreads();
  }
  // mod = ot @ Wo + bo : stage into pf (as u16) then coalesced store
  u16* stg = (u16*)pf;
  const u16* wob = WT + WOT_OFF;
  for (int nt = 0; nt < 8; nt++){
    f32x4 mac[2] = {(f32x4){0.f,0.f,0.f,0.f}, (f32x4){0.f,0.f,0.f,0.f}};
    int c = wv*128 + nt*16 + l15;
    for (int ks = 0; ks < 4; ks++){
      bf16x8 a0 = ld8(ot + l15*136 + ks*32 + q4*8);
      bf16x8 a1 = ld8(ot + (16+l15)*136 + ks*32 + q4*8);
      bf16x8 bb = ld8(wob + (size_t)c*128 + ks*32 + q4*8);
      mac[0] = mfma16(a0, bb, mac[0]);
      mac[1] = mfma16(a1, bb, mac[1]);
    }
    float bv = bs2f(bo[c]);
    for (int mt = 0; mt < 2; mt++) for (int rg = 0; rg < 4; rg++){
      int row = mt*16 + q4*4 + rg;
      stg[row*512 + c] = f2bs(mac[mt][rg] + bv);
    }
  }
  __syncthreads();
  for (int it = 0; it < 8; it++){
    int rr = it*4 + (t >> 6), cc = (t & 63)*8;
    *(u16x8*)(modB + ((size_t)(q0+rr)*8 + b)*512 + cc) = *(const u16x8*)(stg + rr*512 + cc);
  }
}

// ================= k_bands2: 32-row blocks, B direct from L2, X in LDS =================
// Software-pipelined GEMM macros (2-deep register prefetch; no barriers in loop).
// ICE workaround: macros, not functions with accumulator-array params.
#define GEMM32_G(Aptr, Bw)                                                        \
  { for (int mt = 0; mt < 2; mt++) for (int nt = 0; nt < 8; nt++)                 \
      acc[mt][nt] = (f32x4){0.f,0.f,0.f,0.f};                                     \
    const u16* Abase = (Aptr) + (size_t)l15*512 + q4*8;                           \
    const u16* Bbase = (Bw) + (size_t)(w*128 + l15)*512 + q4*8;                   \
    bf16x8 a0c = ld8(Abase);                                                      \
    bf16x8 a1c = ld8(Abase + 16*512);                                             \
    bf16x8 bc[8], bn[8];                                                          \
    for (int nt = 0; nt < 8; nt++) bc[nt] = ld8(Bbase + (size_t)nt*16*512);       \
    for (int ks = 0; ks < 16; ks++){                                              \
      bf16x8 a0n, a1n;                                                            \
      if (ks < 15){                                                               \
        a0n = ld8(Abase + (ks+1)*32);                                             \
        a1n = ld8(Abase + 16*512 + (ks+1)*32);                                    \
        for (int nt = 0; nt < 8; nt++)                                            \
          bn[nt] = ld8(Bbase + (size_t)nt*16*512 + (ks+1)*32);                    \
      }                                                                           \
      for (int nt = 0; nt < 8; nt++){                                             \
        acc[0][nt] = mfma16(a0c, bc[nt], acc[0][nt]);                             \
        acc[1][nt] = mfma16(a1c, bc[nt], acc[1][nt]);                             \
      }                                                                           \
      if (ks < 15){ a0c = a0n; a1c = a1n;                                         \
        for (int nt = 0; nt < 8; nt++) bc[nt] = bn[nt]; }                         \
    } }

#define GEMM32_L(Aptr, Bw)                                                        \
  { for (int mt = 0; mt < 2; mt++) for (int nt = 0; nt < 8; nt++)                 \
      acc[mt][nt] = (f32x4){0.f,0.f,0.f,0.f};                                     \
    const u16* Abase = (Aptr) + l15*520 + q4*8;                                   \
    const u16* Bbase = (Bw) + (size_t)(w*128 + l15)*512 + q4*8;                   \
    bf16x8 a0c = ld8(Abase);                                                      \
    bf16x8 a1c = ld8(Abase + 16*520);                                             \
    bf16x8 bc[8], bn[8];                                                          \
    for (int nt = 0; nt < 8; nt++) bc[nt] = ld8(Bbase + (size_t)nt*16*512);       \
    for (int ks = 0; ks < 16; ks++){                                              \
      bf16x8 a0n, a1n;                                                            \
      if (ks < 15){                                                               \
        a0n = ld8(Abase + (ks+1)*32);                                             \
        a1n = ld8(Abase + 16*520 + (ks+1)*32);                                    \
        for (int nt = 0; nt < 8; nt++)                                            \
          bn[nt] = ld8(Bbase + (size_t)nt*16*512 + (ks+1)*32);                    \
      }                                                                           \
      for (int nt = 0; nt < 8; nt++){                                             \
        acc[0][nt] = mfma16(a0c, bc[nt], acc[0][nt]);                             \
        acc[1][nt] = mfma16(a1c, bc[nt], acc[1][nt]);                             \
      }                                                                           \
      if (ks < 15){ a0c = a0n; a1c = a1n;                                         \
        for (int nt = 0; nt < 8; nt++) bc[nt] = bn[nt]; }                         \
    } }

__global__ __launch_bounds__(256, 2) void k_bands2(const u16* canon, const u16* modB,
      const u16* WT, const u16* hlB, const unsigned* flag, void* outv){
  int t = threadIdx.x, rgp = blockIdx.x;
  int lane = t & 63, w = t >> 6, l15 = lane & 15, q4 = lane >> 4;
  __shared__ __align__(16) u16 xa[32*520];
  __shared__ __align__(16) u16 xb[32*520];
  __shared__ float projacc[384];   // [w][row][o] = ((w*32)+row)*3+o
  for (int e = t; e < 384; e += 256) projacc[e] = 0.f;
  __syncthreads();
  const u16* Agl = modB + (size_t)rgp*32*512;
  const u16* hl0 = hlB;
  const u16* hl1 = hlB + (size_t)HWQ*512;
  const u16* hl2 = hlB + (size_t)2*HWQ*512;
  int qbase = rgp*4;
  f32x4 acc[2][8];

  // ---- g1: X1 = relu(mod@W0 + b0 + hl0) -> xa ; proj0 ----
  GEMM32_G(Agl, WT + MODT_OFF);
  {
    float ow[8][3], bias[8];
    for (int nt = 0; nt < 8; nt++){
      int c = w*128 + nt*16 + l15;
      bias[nt] = bs2f(canon[C_MODB + c]);
      for (int o = 0; o < 3; o++) ow[nt][o] = bs2f(canon[C_OUTW + c*3 + o]);
    }
    for (int mt = 0; mt < 2; mt++) for (int rg = 0; rg < 4; rg++){
      int row = mt*16 + q4*4 + rg;
      int q = qbase + (row >> 3);
      float p0 = 0.f, p1 = 0.f, p2 = 0.f;
      for (int nt = 0; nt < 8; nt++){
        int c = w*128 + nt*16 + l15;
        float v = acc[mt][nt][rg] + bias[nt] + bs2f(hl0[(size_t)q*512 + c]);
        v = fmaxf(v, 0.f);
        xa[row*520 + c] = f2bs(v);
        p0 += v*ow[nt][0]; p1 += v*ow[nt][1]; p2 += v*ow[nt][2];
      }
      for (int m = 1; m < 16; m <<= 1){
        p0 += __shfl_xor(p0, m, 64); p1 += __shfl_xor(p1, m, 64); p2 += __shfl_xor(p2, m, 64);
      }
      if (l15 == 0){
        projacc[(w*32 + row)*3 + 0] += p0;
        projacc[(w*32 + row)*3 + 1] += p1;
        projacc[(w*32 + row)*3 + 2] += p2;
      }
    }
  }
  __syncthreads();

  // ---- g2: X2 = relu(mod@W1 + b1 + hl1) + X1 -> xb ----
  GEMM32_G(Agl, WT + MODT_OFF + 262144);
  {
    float bias[8];
    for (int nt = 0; nt < 8; nt++) bias[nt] = bs2f(canon[C_MODB + 512 + w*128 + nt*16 + l15]);
    for (int mt = 0; mt < 2; mt++) for (int rg = 0; rg < 4; rg++){
      int row = mt*16 + q4*4 + rg;
      int q = qbase + (row >> 3);
      for (int nt = 0; nt < 8; nt++){
        int c = w*128 + nt*16 + l15;
        float v = acc[mt][nt][rg] + bias[nt] + bs2f(hl1[(size_t)q*512 + c]);
        v = fmaxf(v, 0.f) + bs2f(xa[row*520 + c]);
        xb[row*520 + c] = f2bs(v);
      }
    }
  }
  __syncthreads();

  // ---- g3: X3 = relu(X2@hv0 + hvb0) -> xa ; proj1 ----
  GEMM32_L(xb, WT + HVT_OFF);
  {
    float ow[8][3], bias[8];
    for (int nt = 0; nt < 8; nt++){
      int c = w*128 + nt*16 + l15;
      bias[nt] = bs2f(canon[C_HVB + c]);
      for (int o = 0; o < 3; o++) ow[nt][o] = bs2f(canon[C_OUTW + 1536 + c*3 + o]);
    }
    for (int mt = 0; mt < 2; mt++) for (int rg = 0; rg < 4; rg++){
      int row = mt*16 + q4*4 + rg;
      float p0 = 0.f, p1 = 0.f, p2 = 0.f;
      for (int nt = 0; nt < 8; nt++){
        int c = w*128 + nt*16 + l15;
        float v = fmaxf(acc[mt][nt][rg] + bias[nt], 0.f);
        xa[row*520 + c] = f2bs(v);
        p0 += v*ow[nt][0]; p1 += v*ow[nt][1]; p2 += v*ow[nt][2];
      }
      for (int m = 1; m < 16; m <<= 1){
        p0 += __shfl_xor(p0, m, 64); p1 += __shfl_xor(p1, m, 64); p2 += __shfl_xor(p2, m, 64);
      }
      if (l15 == 0){
        projacc[(w*32 + row)*3 + 0] += p0;
        projacc[(w*32 + row)*3 + 1] += p1;
        projacc[(w*32 + row)*3 + 2] += p2;
      }
    }
  }
  __syncthreads();

  // ---- g4: X4 = relu(mod@W2 + b2 + hl2) + X3 -> xb ----
  GEMM32_G(Agl, WT + MODT_OFF + 524288);
  {
    float bias[8];
    for (int nt = 0; nt < 8; nt++) bias[nt] = bs2f(canon[C_MODB + 1024 + w*128 + nt*16 + l15]);
    for (int mt = 0; mt < 2; mt++) for (int rg = 0; rg < 4; rg++){
      int row = mt*16 + q4*4 + rg;
      int q = qbase + (row >> 3);
      for (int nt = 0; nt < 8; nt++){
        int c = w*128 + nt*16 + l15;
        float v = acc[mt][nt][rg] + bias[nt] + bs2f(hl2[(size_t)q*512 + c]);
        v = fmaxf(v, 0.f) + bs2f(xa[row*520 + c]);
        xb[row*520 + c] = f2bs(v);
      }
    }
  }
  __syncthreads();

  // ---- g5: X5 = relu(X4@hv1 + hvb1) ; proj2 only ----
  GEMM32_L(xb, WT + HVT_OFF + 262144);
  {
    float ow[8][3], bias[8];
    for (int nt = 0; nt < 8; nt++){
      int c = w*128 + nt*16 + l15;
      bias[nt] = bs2f(canon[C_HVB + 512 + c]);
      for (int o = 0; o < 3; o++) ow[nt][o] = bs2f(canon[C_OUTW + 3072 + c*3 + o]);
    }
    for (int mt = 0; mt < 2; mt++) for (int rg = 0; rg < 4; rg++){
      int row = mt*16 + q4*4 + rg;
      float p0 = 0.f, p1 = 0.f, p2 = 0.f;
      for (int nt = 0; nt < 8; nt++){
        float v = fmaxf(acc[mt][nt][rg] + bias[nt], 0.f);
        p0 += v*ow[nt][0]; p1 += v*ow[nt][1]; p2 += v*ow[nt][2];
      }
      for (int m = 1; m < 16; m <<= 1){
        p0 += __shfl_xor(p0, m, 64); p1 += __shfl_xor(p1, m, 64); p2 += __shfl_xor(p2, m, 64);
      }
      if (l15 == 0){
        projacc[(w*32 + row)*3 + 0] += p0;
        projacc[(w*32 + row)*3 + 1] += p1;
        projacc[(w*32 + row)*3 + 2] += p2;
      }
    }
  }
  __syncthreads();

  // ---- final: reduce proj over waves, add biases, store ----
  if (t < 96){
    int row = t / 3, o = t - (t/3)*3;
    float s = bs2f(canon[C_OUTB + o]) + bs2f(canon[C_OUTB + 3 + o]) + bs2f(canon[C_OUTB + 6 + o]);
    for (int w2 = 0; w2 < 4; w2++) s += projacc[(w2*32 + row)*3 + o];
    int gr = rgp*32 + row;
    int b = gr & 7, q = gr >> 3;
    size_t idx = ((size_t)b*HWQ + q)*3 + o;
    if (*flag) ((float*)outv)[idx] = s;
    else       ((u16*)outv)[idx]   = f2bs(s);
  }
}

extern "C" void kernel_launch(void* const* d_in, const int* in_sizes, int n_in,
                              void* d_out, int out_size, void* d_ws, size_t ws_size,
                              hipStream_t stream){
  (void)in_sizes; (void)n_in; (void)out_size;

  u16* wsp   = (u16*)d_ws;
  unsigned* flag = (unsigned*)wsp;
  u16* canon = wsp + 8;
  u16* WT    = canon + CANON_PAD;
  u16* kpart = WT + 1703936;
  u16* vT    = kpart + 262144;
  u16* qvecB = vT + 262144;
  u16* hlB   = qvecB + 2097152;
  u16* modB  = hlB + 25165824;
  if (ws_size < 199773250ULL) return;

  SrcPtrs sp;
  for (int i = 0; i < 16; i++) sp.p[i] = d_in[i];
  const float* xraw = (const float*)d_in[0];

  k_detect <<<1, 256, 0, stream>>>((const u16*)d_in[3], flag);
  k_convert<<<(C_TOTAL + 255)/256, 256, 0, stream>>>(sp, flag, canon);
  k_tr     <<<1664, 256, 0, stream>>>(canon, WT);
  k_kv     <<<2048, 256, 0, stream>>>(canon, kpart, vT);
  k_query  <<<1024, 256, 0, stream>>>(canon, xraw, flag, WT, qvecB, hlB);
  k_attn   <<<4096, 256, 0, stream>>>(canon, xraw, flag, qvecB, kpart, vT, WT, modB);
  k_bands2 <<<4096, 256, 0, stream>>>(canon, modB, WT, hlB, flag, d_out);
}

// Round 12
// 1523.593 us; speedup vs baseline: 3.9194x; 1.1519x over previous
//
#include <hip/hip_runtime.h>
#include <math.h>

typedef unsigned short u16;
typedef unsigned int uint;
typedef __bf16 bf16x8 __attribute__((ext_vector_type(8)));
typedef unsigned short u16x8 __attribute__((ext_vector_type(8)));
typedef float f32x4 __attribute__((ext_vector_type(4)));

#define HWQ 16384
#define PI_F 3.14159265358979323846f

// canonical (bf16) input offsets inside ws
#define C_X     0
#define C_TOK   262144
#define C_QW    1310720
#define C_QB    1376256
#define C_WQ    1376768
#define C_WKV   1442304
#define C_WO    1704448
#define C_BO    1769984
#define C_BWW   1770496
#define C_BWB   1967104
#define C_MODW  1968640
#define C_MODB  2755072
#define C_HVW   2756608
#define C_HVB   3280896
#define C_OUTW  3281920
#define C_OUTB  3286528
#define C_TOTAL 3286537
#define CANON_PAD 3286544

// WT (transposed weights) element offsets (relative to WT base)
#define QWT_OFF  0
#define WQT_OFF  65536
#define WOT_OFF  131072
#define BWT_OFF  196608
#define MODT_OFF 393216
#define HVT_OFF  1179648

struct SrcPtrs { const void* p[16]; };

__device__ __forceinline__ float bs2f(u16 u){
  unsigned v = ((unsigned)u) << 16; float f; __builtin_memcpy(&f, &v, 4); return f;
}
__device__ __forceinline__ u16 f2bs(float f){
  unsigned v; __builtin_memcpy(&v, &f, 4);
  v = (v + 0x7fffu + ((v >> 16) & 1u)) >> 16;
  return (u16)v;
}
__device__ __forceinline__ f32x4 mfma16(bf16x8 a, bf16x8 b, f32x4 c){
  return __builtin_amdgcn_mfma_f32_16x16x32_bf16(a, b, c, 0, 0, 0);
}
__device__ __forceinline__ bf16x8 ld8(const u16* p){ return *(const bf16x8*)p; }
__device__ __forceinline__ void ld2lds(const u16* g, u16* l){
  __builtin_amdgcn_global_load_lds((__attribute__((address_space(1))) const uint*)g,
                                   (__attribute__((address_space(3))) uint*)l, 16, 0, 0);
}

// ---------------- dtype detect ----------------
__global__ void k_detect(const u16* qb_raw, unsigned* flag){
  __shared__ int cnt[256];
  int t = threadIdx.x;
  u16 u = qb_raw[2*t];
  int e = (u >> 7) & 0xFF;
  cnt[t] = (e >= 126) ? 1 : 0;
  __syncthreads();
  for (int s = 128; s > 0; s >>= 1){
    if (t < s) cnt[t] += cnt[t + s];
    __syncthreads();
  }
  if (t == 0) *flag = (cnt[0] >= 16) ? 1u : 0u;
}

// ---------------- convert inputs to canonical bf16 ----------------
__global__ __launch_bounds__(256) void k_convert(SrcPtrs sp, const unsigned* flag, u16* canon){
  const int offs[17] = {C_X,C_TOK,C_QW,C_QB,C_WQ,C_WKV,C_WO,C_BO,C_BWW,C_BWB,
                        C_MODW,C_MODB,C_HVW,C_HVB,C_OUTW,C_OUTB,C_TOTAL};
  int e = blockIdx.x * 256 + threadIdx.x;
  if (e >= C_TOTAL) return;
  int seg = 0;
  for (int i = 1; i < 16; i++) if (e >= offs[i]) seg = i;
  int local = e - offs[seg];
  if (*flag) canon[e] = f2bs(((const float*)sp.p[seg])[local]);
  else       canon[e] = ((const u16*)sp.p[seg])[local];
}

// ---------------- weight transpose ----------------
__global__ __launch_bounds__(256) void k_tr(const u16* canon, u16* WT){
  __shared__ u16 tile[32][33];
  int bid = blockIdx.x, t = threadIdx.x;
  const u16* src; u16* dst; int K, N, tl;
  if (bid < 384){
    int m = bid >> 6; tl = bid & 63;
    if (m == 0){ src = canon + C_QW;  dst = WT + QWT_OFF; K = 128; N = 512; }
    else if (m == 1){ src = canon + C_WQ; dst = WT + WQT_OFF; K = 512; N = 128; }
    else if (m == 2){ src = canon + C_WO; dst = WT + WOT_OFF; K = 128; N = 512; }
    else { src = canon + C_BWW + (m-3)*65536; dst = WT + BWT_OFF + (m-3)*65536; K = 128; N = 512; }
  } else if (bid < 1152){
    int m = (bid - 384) >> 8; tl = (bid - 384) & 255;
    src = canon + C_MODW + m*262144; dst = WT + MODT_OFF + m*262144; K = 512; N = 512;
  } else {
    int m = (bid - 1152) >> 8; tl = (bid - 1152) & 255;
    src = canon + C_HVW + m*262144; dst = WT + HVT_OFF + m*262144; K = 512; N = 512;
  }
  int kt = K >> 5;
  int k0 = (tl % kt) * 32, n0 = (tl / kt) * 32;
  int tx = t & 31, ty = t >> 5;
  for (int r = 0; r < 4; r++)
    tile[ty + r*8][tx] = src[(size_t)(k0 + ty + r*8) * N + n0 + tx];
  __syncthreads();
  for (int r = 0; r < 4; r++)
    dst[(size_t)(n0 + ty + r*8) * K + k0 + tx] = tile[tx][ty + r*8];
}

// ---------------- kv = tokens @ Wkv ----------------
__global__ __launch_bounds__(256) void k_kv(const u16* canon, u16* kpart, u16* vT){
  int b = blockIdx.x >> 8, kk = blockIdx.x & 255, t = threadIdx.x;
  const u16* tok = canon + C_TOK;
  const u16* Wkv = canon + C_WKV;
  __shared__ float tk[512];
  const u16* tr = tok + ((size_t)(b*256 + kk)) * 512;
  tk[t] = bs2f(tr[t]); tk[t+256] = bs2f(tr[t+256]);
  __syncthreads();
  float acc = 0.f;
  for (int k = 0; k < 512; k++) acc += tk[k] * bs2f(Wkv[k*256 + t]);
  if (t < 128) kpart[((size_t)(b*256 + kk))*128 + t] = f2bs(acc);
  else vT[((size_t)b*128 + (t-128))*256 + kk] = f2bs(acc);
}

// ---------------- per-query: gamma -> xq -> qvec ; h_l bands ----------------
__global__ __launch_bounds__(256) void k_query(const u16* canon, const float* xraw,
      const unsigned* flag, const u16* WT, u16* qvecB, u16* hlB){
  int t = threadIdx.x, q0 = blockIdx.x * 16;
  const u16* q_b = canon + C_QB;
  const u16* bw_b= canon + C_BWB;
  int lane = t & 63, wv = t >> 6, l15 = lane & 15, q4 = lane >> 4;
  __shared__ __align__(16) u16 g[16*136];
  __shared__ __align__(16) u16 xql[16*520];
  __shared__ float cco[32];
  __shared__ float omg[32];
  for (int e = t; e < 16*136; e += 256) g[e] = 0;
  for (int e = t; e < 16*520; e += 256) xql[e] = 0;
  if (t < 32) cco[t] = (*flag) ? xraw[q0*2 + t] : bs2f(canon[C_X + q0*2 + t]);
  if (t < 32) omg[t] = (float)pow(10.0, 1.0 + t * ((2.1072099696478683 - 1.0)/31.0));
  __syncthreads();
  for (int i = 0; i < 8; i++){
    int id = i*256 + t, qi = id >> 7, f = id & 127;
    int d = f >> 6, r = f & 63, fi = r & 31;
    float arg = PI_F * cco[qi*2 + d] * omg[fi];
    g[qi*136 + f] = f2bs((r < 32) ? sinf(arg) : cosf(arg));
  }
  __syncthreads();
  { // xq = relu(g @ q_W + q_b) -> xql
    const u16* Bm = WT + QWT_OFF;
    for (int nt = 0; nt < 8; nt++){
      f32x4 acc = {0.f,0.f,0.f,0.f};
      int c = wv*128 + nt*16 + l15;
      for (int ks = 0; ks < 4; ks++){
        bf16x8 a  = ld8(g + l15*136 + ks*32 + q4*8);
        bf16x8 bb = ld8(Bm + (size_t)c*128 + ks*32 + q4*8);
        acc = mfma16(a, bb, acc);
      }
      float qb = bs2f(q_b[c]);
      for (int rg = 0; rg < 4; rg++){
        int row = q4*4 + rg;
        xql[row*520 + c] = f2bs(fmaxf(acc[rg] + qb, 0.f));
      }
    }
  }
  __syncthreads();
  { // qvec = xq @ Wq -> stage in g -> coalesced store
    const u16* Bm = WT + WQT_OFF;
    for (int nh = 0; nh < 2; nh++){
      f32x4 acc = {0.f,0.f,0.f,0.f};
      int c = wv*32 + nh*16 + l15;
      for (int ks = 0; ks < 16; ks++){
        bf16x8 a  = ld8(xql + l15*520 + ks*32 + q4*8);
        bf16x8 bb = ld8(Bm + (size_t)c*512 + ks*32 + q4*8);
        acc = mfma16(a, bb, acc);
      }
      for (int rg = 0; rg < 4; rg++)
        g[(q4*4 + rg)*128 + c] = f2bs(acc[rg]);
    }
    __syncthreads();
    {
      int rr = t >> 4, cc = (t & 15)*8;
      *(u16x8*)(qvecB + (size_t)(q0 + rr)*128 + cc) = *(const u16x8*)(g + rr*128 + cc);
    }
  }
  const double LG[3] = {1.2041199826559248, 1.8061799739838869, 2.4082399653118496};
  for (int ib = 0; ib < 3; ib++){
    __syncthreads();
    if (t < 32) omg[t] = (float)pow(10.0, 1.0 + t * ((LG[ib] - 1.0)/31.0));
    __syncthreads();
    for (int i = 0; i < 8; i++){
      int id = i*256 + t, qi = id >> 7, f = id & 127;
      int d = f >> 6, r = f & 63, fi = r & 31;
      float arg = PI_F * cco[qi*2 + d] * omg[fi];
      g[qi*136 + f] = f2bs((r < 32) ? sinf(arg) : cosf(arg));
    }
    __syncthreads();
    const u16* Bm = WT + BWT_OFF + ib*65536;
    for (int nt = 0; nt < 8; nt++){
      f32x4 acc = {0.f,0.f,0.f,0.f};
      int c = wv*128 + nt*16 + l15;
      for (int ks = 0; ks < 4; ks++){
        bf16x8 a  = ld8(g + l15*136 + ks*32 + q4*8);
        bf16x8 bb = ld8(Bm + (size_t)c*128 + ks*32 + q4*8);
        acc = mfma16(a, bb, acc);
      }
      float bias = bs2f(bw_b[ib*512 + c]);
      for (int rg = 0; rg < 4; rg++)
        xql[(q4*4 + rg)*520 + c] = f2bs(fmaxf(acc[rg] + bias, 0.f));
    }
    __syncthreads();
    for (int it = 0; it < 4; it++){
      int rr = it*4 + (t >> 6), cc = (t & 63)*8;
      *(u16x8*)(hlB + ((size_t)ib*HWQ + q0 + rr)*512 + cc) = *(const u16x8*)(xql + rr*520 + cc);
    }
  }
}

// ---------------- attention + mod projection (f32 softmax, staged store) ----------------
__global__ __launch_bounds__(256) void k_attn(const u16* canon, const float* xraw,
      const unsigned* flag, const u16* qvecB, const u16* kpart, const u16* vT,
      const u16* WT, u16* modB){
  int t = threadIdx.x;
  int b = blockIdx.x & 7, qt = blockIdx.x >> 3, q0 = qt*32;
  const u16* bo = canon + C_BO;
  int lane = t & 63, wv = t >> 6, l15 = lane & 15, q4 = lane >> 4;
  __shared__ __align__(16) u16 ql[32*136];
  __shared__ __align__(16) u16 pl[32*264];
  __shared__ __align__(16) float pf[32*264];
  __shared__ __align__(16) u16 ot[32*136];
  __shared__ float tqs[32];
  __shared__ float red[256];
  __shared__ float rst[32];
  for (int e = t; e < 32*136; e += 256){ ql[e] = 0; ot[e] = 0; }
  for (int e = t; e < 32*264; e += 256) pl[e] = 0;
  __syncthreads();
  for (int i = 0; i < 16; i++){
    int id = i*256 + t, qi = id >> 7, c = id & 127;
    ql[qi*136 + c] = qvecB[(size_t)(q0 + qi)*128 + c];
  }
  if (t < 32){
    float c0, c1;
    if (*flag){ c0 = xraw[(q0+t)*2]; c1 = xraw[(q0+t)*2 + 1]; }
    else { c0 = bs2f(canon[C_X + (q0+t)*2]); c1 = bs2f(canon[C_X + (q0+t)*2 + 1]); }
    int rr = (int)(c0*16.f), cc = (int)(c1*16.f);
    tqs[t] = (float)(rr*16 + cc) * (1.f/256.f);
  }
  __syncthreads();
  for (int h = 0; h < 2; h++){
    f32x4 sac[2][4];
    for (int mt = 0; mt < 2; mt++) for (int nt = 0; nt < 4; nt++) sac[mt][nt] = (f32x4){0.f,0.f,0.f,0.f};
    const u16* kb = kpart + (size_t)b*256*128 + h*64;
    for (int ks = 0; ks < 2; ks++){
      bf16x8 a0 = ld8(ql + l15*136 + h*64 + ks*32 + q4*8);
      bf16x8 a1 = ld8(ql + (16+l15)*136 + h*64 + ks*32 + q4*8);
      for (int nt = 0; nt < 4; nt++){
        int kk = wv*64 + nt*16 + l15;
        bf16x8 bb = ld8(kb + (size_t)kk*128 + ks*32 + q4*8);
        sac[0][nt] = mfma16(a0, bb, sac[0][nt]);
        sac[1][nt] = mfma16(a1, bb, sac[1][nt]);
      }
    }
    for (int mt = 0; mt < 2; mt++) for (int nt = 0; nt < 4; nt++){
      int kk = wv*64 + nt*16 + l15;
      float pos = ((float)kk + 0.5f) * (1.f/256.f);
      for (int rg = 0; rg < 4; rg++){
        int row = mt*16 + q4*4 + rg;
        float dd = tqs[row] - pos;
        pf[row*264 + kk] = sac[mt][nt][rg]*0.125f - 10.f*dd*dd;
      }
    }
    __syncthreads();
    {
      int r = t >> 3, i = t & 7;
      float* pr = pf + r*264 + i*32;
      u16* po = pl + r*264 + i*32;
      float m = -1e30f;
      for (int j = 0; j < 32; j++) m = fmaxf(m, pr[j]);
      red[t] = m;
      __syncthreads();
      if (t < 32){ float mm = red[t*8];
        for (int j = 1; j < 8; j++) mm = fmaxf(mm, red[t*8+j]);
        rst[t] = mm; }
      __syncthreads();
      float mm = rst[r], sum = 0.f;
      for (int j = 0; j < 32; j++){ float e = expf(pr[j] - mm); pr[j] = e; sum += e; }
      red[t] = sum;
      __syncthreads();
      if (t < 32){ float ss = 0.f;
        for (int j = 0; j < 8; j++) ss += red[t*8+j];
        rst[t] = 1.f/ss; }
      __syncthreads();
      float inv = rst[r];
      for (int j = 0; j < 32; j++) po[j] = f2bs(pr[j] * inv);
    }
    __syncthreads();
    f32x4 oac[2] = {(f32x4){0.f,0.f,0.f,0.f}, (f32x4){0.f,0.f,0.f,0.f}};
    const u16* vb = vT + ((size_t)b*128 + h*64)*256;
    int dl = wv*16 + l15;
    for (int ks = 0; ks < 8; ks++){
      bf16x8 a0 = ld8(pl + l15*264 + ks*32 + q4*8);
      bf16x8 a1 = ld8(pl + (16+l15)*264 + ks*32 + q4*8);
      bf16x8 bb = ld8(vb + (size_t)dl*256 + ks*32 + q4*8);
      oac[0] = mfma16(a0, bb, oac[0]);
      oac[1] = mfma16(a1, bb, oac[1]);
    }
    for (int mt = 0; mt < 2; mt++) for (int rg = 0; rg < 4; rg++){
      int row = mt*16 + q4*4 + rg;
      ot[row*136 + h*64 + dl] = f2bs(oac[mt][rg]);
    }
    __syncthreads();
  }
  u16* stg = (u16*)pf;
  const u16* wob = WT + WOT_OFF;
  for (int nt = 0; nt < 8; nt++){
    f32x4 mac[2] = {(f32x4){0.f,0.f,0.f,0.f}, (f32x4){0.f,0.f,0.f,0.f}};
    int c = wv*128 + nt*16 + l15;
    for (int ks = 0; ks < 4; ks++){
      bf16x8 a0 = ld8(ot + l15*136 + ks*32 + q4*8);
      bf16x8 a1 = ld8(ot + (16+l15)*136 + ks*32 + q4*8);
      bf16x8 bb = ld8(wob + (size_t)c*128 + ks*32 + q4*8);
      mac[0] = mfma16(a0, bb, mac[0]);
      mac[1] = mfma16(a1, bb, mac[1]);
    }
    float bv = bs2f(bo[c]);
    for (int mt = 0; mt < 2; mt++) for (int rg = 0; rg < 4; rg++){
      int row = mt*16 + q4*4 + rg;
      stg[row*512 + c] = f2bs(mac[mt][rg] + bv);
    }
  }
  __syncthreads();
  for (int it = 0; it < 8; it++){
    int rr = it*4 + (t >> 6), cc = (t & 63)*8;
    *(u16x8*)(modB + ((size_t)(q0+rr)*8 + b)*512 + cc) = *(const u16x8*)(stg + rr*512 + cc);
  }
}

// ================= k_bands3: M=64/block, 512 thr, global_load_lds staged B/A =================
// Wave w owns cols [w*64, w*64+64). Residuals X1/X3 kept in registers; X2/X4 in XL.
// Macros (ICE workaround: no acc-array function params).
#define STAGE_B(Bw, ks)                                                          \
  { const u16* gb = (Bw) + (size_t)(w*64)*512 + (ks)*32 + (lane>>4)*8            \
                         + (size_t)(lane & 15)*512;                              \
    for (int j = 0; j < 4; j++)                                                  \
      ld2lds(gb + (size_t)(j*16)*512, Bst + w*2048 + j*512); }

#define STAGE_A(Agl, ks)                                                         \
  if (w < 4){                                                                    \
    const u16* gp = (Agl) + (size_t)(w*16 + (lane>>2))*512 + (ks)*32 + (lane&3)*8; \
    ld2lds(gp, Ast + w*512); }

#define ZACC for (int mt = 0; mt < 4; mt++) for (int nt = 0; nt < 4; nt++) acc[mt][nt] = (f32x4){0.f,0.f,0.f,0.f};

#define GEMMG(Agl, Bw)                                                           \
  { ZACC                                                                         \
    for (int ks = 0; ks < 16; ks++){                                             \
      __syncthreads();                                                           \
      STAGE_B(Bw, ks); STAGE_A(Agl, ks);                                         \
      __syncthreads();                                                           \
      bf16x8 bf0 = ld8(Bst + w*2048 + 0*512 + q4*128 + l15*8);                   \
      bf16x8 bf1 = ld8(Bst + w*2048 + 1*512 + q4*128 + l15*8);                   \
      bf16x8 bf2 = ld8(Bst + w*2048 + 2*512 + q4*128 + l15*8);                   \
      bf16x8 bf3 = ld8(Bst + w*2048 + 3*512 + q4*128 + l15*8);                   \
      for (int mt = 0; mt < 4; mt++){                                            \
        bf16x8 af = ld8(Ast + (mt*16 + l15)*32 + q4*8);                          \
        acc[mt][0] = mfma16(af, bf0, acc[mt][0]);                                \
        acc[mt][1] = mfma16(af, bf1, acc[mt][1]);                                \
        acc[mt][2] = mfma16(af, bf2, acc[mt][2]);                                \
        acc[mt][3] = mfma16(af, bf3, acc[mt][3]);                                \
      } } }

#define GEMML(Bw)                                                                \
  { ZACC                                                                         \
    for (int ks = 0; ks < 16; ks++){                                             \
      __syncthreads();                                                           \
      STAGE_B(Bw, ks);                                                           \
      __syncthreads();                                                           \
      bf16x8 bf0 = ld8(Bst + w*2048 + 0*512 + q4*128 + l15*8);                   \
      bf16x8 bf1 = ld8(Bst + w*2048 + 1*512 + q4*128 + l15*8);                   \
      bf16x8 bf2 = ld8(Bst + w*2048 + 2*512 + q4*128 + l15*8);                   \
      bf16x8 bf3 = ld8(Bst + w*2048 + 3*512 + q4*128 + l15*8);                   \
      for (int mt = 0; mt < 4; mt++){                                            \
        bf16x8 af = ld8(XL + (mt*16 + l15)*520 + ks*32 + q4*8);                  \
        acc[mt][0] = mfma16(af, bf0, acc[mt][0]);                                \
        acc[mt][1] = mfma16(af, bf1, acc[mt][1]);                                \
        acc[mt][2] = mfma16(af, bf2, acc[mt][2]);                                \
        acc[mt][3] = mfma16(af, bf3, acc[mt][3]);                                \
      } } }

#define PROJ_REDUCE                                                              \
  __syncthreads();                                                               \
  if (t < 192){ float s = 0.f;                                                   \
    for (int w2 = 0; w2 < 8; w2++) s += pscr[w2*192 + t];                        \
    totrow[t] += s; }                                                            \
  __syncthreads();

__global__ __launch_bounds__(512, 2) void k_bands3(const u16* canon, const u16* modB,
      const u16* WT, const u16* hlB, const unsigned* flag, void* outv){
  int t = threadIdx.x, rgp = blockIdx.x;
  int lane = t & 63, w = t >> 6, l15 = lane & 15, q4 = lane >> 4;
  __shared__ __align__(16) u16 XL[64*520];     // 66,560 B
  __shared__ __align__(16) u16 Bst[8*2048];    // 32,768 B
  __shared__ __align__(16) u16 Ast[2048];      //  4,096 B
  __shared__ float pscr[1536];                 //  6,144 B
  __shared__ float totrow[192];                //    768 B
  if (t < 192){
    int o = t - (t/3)*3;
    totrow[t] = bs2f(canon[C_OUTB + o]) + bs2f(canon[C_OUTB + 3 + o]) + bs2f(canon[C_OUTB + 6 + o]);
  }
  const u16* Agl = modB + (size_t)rgp*64*512;
  const u16* hl0 = hlB;
  const u16* hl1 = hlB + (size_t)HWQ*512;
  const u16* hl2 = hlB + (size_t)2*HWQ*512;
  int qbase = rgp*8;   // 64 rows = 8 q-groups
  f32x4 acc[4][4];
  f32x4 xr[4][4];      // residual keep (X1 then X3)

  // ---- g1: X1 = relu(mod@W0 + b0 + hl0) -> regs ; proj0 ----
  GEMMG(Agl, WT + MODT_OFF);
  {
    float ow[4][3], bias[4];
    for (int nt = 0; nt < 4; nt++){
      int c = w*64 + nt*16 + l15;
      bias[nt] = bs2f(canon[C_MODB + c]);
      for (int o = 0; o < 3; o++) ow[nt][o] = bs2f(canon[C_OUTW + c*3 + o]);
    }
    for (int mt = 0; mt < 4; mt++) for (int rg = 0; rg < 4; rg++){
      int row = mt*16 + q4*4 + rg;
      int q = qbase + (row >> 3);
      float p0 = 0.f, p1 = 0.f, p2 = 0.f;
      for (int nt = 0; nt < 4; nt++){
        int c = w*64 + nt*16 + l15;
        float v = acc[mt][nt][rg] + bias[nt] + bs2f(hl0[(size_t)q*512 + c]);
        v = fmaxf(v, 0.f);
        xr[mt][nt][rg] = v;
        p0 += v*ow[nt][0]; p1 += v*ow[nt][1]; p2 += v*ow[nt][2];
      }
      for (int m = 1; m < 16; m <<= 1){
        p0 += __shfl_xor(p0, m, 64); p1 += __shfl_xor(p1, m, 64); p2 += __shfl_xor(p2, m, 64);
      }
      if (l15 == 0){
        pscr[w*192 + row*3 + 0] = p0;
        pscr[w*192 + row*3 + 1] = p1;
        pscr[w*192 + row*3 + 2] = p2;
      }
    }
  }
  PROJ_REDUCE;

  // ---- g2: X2 = relu(mod@W1 + b1 + hl1) + X1 -> XL ----
  GEMMG(Agl, WT + MODT_OFF + 262144);
  {
    float bias[4];
    for (int nt = 0; nt < 4; nt++) bias[nt] = bs2f(canon[C_MODB + 512 + w*64 + nt*16 + l15]);
    for (int mt = 0; mt < 4; mt++) for (int rg = 0; rg < 4; rg++){
      int row = mt*16 + q4*4 + rg;
      int q = qbase + (row >> 3);
      for (int nt = 0; nt < 4; nt++){
        int c = w*64 + nt*16 + l15;
        float v = acc[mt][nt][rg] + bias[nt] + bs2f(hl1[(size_t)q*512 + c]);
        v = fmaxf(v, 0.f) + xr[mt][nt][rg];
        XL[row*520 + c] = f2bs(v);
      }
    }
  }
  __syncthreads();

  // ---- g3: X3 = relu(X2@hv0 + hvb0) -> regs ; proj1 ----
  GEMML(WT + HVT_OFF);
  {
    float ow[4][3], bias[4];
    for (int nt = 0; nt < 4; nt++){
      int c = w*64 + nt*16 + l15;
      bias[nt] = bs2f(canon[C_HVB + c]);
      for (int o = 0; o < 3; o++) ow[nt][o] = bs2f(canon[C_OUTW + 1536 + c*3 + o]);
    }
    for (int mt = 0; mt < 4; mt++) for (int rg = 0; rg < 4; rg++){
      int row = mt*16 + q4*4 + rg;
      float p0 = 0.f, p1 = 0.f, p2 = 0.f;
      for (int nt = 0; nt < 4; nt++){
        float v = fmaxf(acc[mt][nt][rg] + bias[nt], 0.f);
        xr[mt][nt][rg] = v;
        p0 += v*ow[nt][0]; p1 += v*ow[nt][1]; p2 += v*ow[nt][2];
      }
      for (int m = 1; m < 16; m <<= 1){
        p0 += __shfl_xor(p0, m, 64); p1 += __shfl_xor(p1, m, 64); p2 += __shfl_xor(p2, m, 64);
      }
      if (l15 == 0){
        pscr[w*192 + row*3 + 0] = p0;
        pscr[w*192 + row*3 + 1] = p1;
        pscr[w*192 + row*3 + 2] = p2;
      }
    }
  }
  PROJ_REDUCE;

  // ---- g4: X4 = relu(mod@W2 + b2 + hl2) + X3 -> XL ----
  GEMMG(Agl, WT + MODT_OFF + 524288);
  {
    float bias[4];
    for (int nt = 0; nt < 4; nt++) bias[nt] = bs2f(canon[C_MODB + 1024 + w*64 + nt*16 + l15]);
    for (int mt = 0; mt < 4; mt++) for (int rg = 0; rg < 4; rg++){
      int row = mt*16 + q4*4 + rg;
      int q = qbase + (row >> 3);
      for (int nt = 0; nt < 4; nt++){
        int c = w*64 + nt*16 + l15;
        float v = acc[mt][nt][rg] + bias[nt] + bs2f(hl2[(size_t)q*512 + c]);
        v = fmaxf(v, 0.f) + xr[mt][nt][rg];
        XL[row*520 + c] = f2bs(v);
      }
    }
  }
  __syncthreads();

  // ---- g5: X5 = relu(X4@hv1 + hvb1) ; proj2 ----
  GEMML(WT + HVT_OFF + 262144);
  {
    float ow[4][3], bias[4];
    for (int nt = 0; nt < 4; nt++){
      int c = w*64 + nt*16 + l15;
      bias[nt] = bs2f(canon[C_HVB + 512 + c]);
      for (int o = 0; o < 3; o++) ow[nt][o] = bs2f(canon[C_OUTW + 3072 + c*3 + o]);
    }
    for (int mt = 0; mt < 4; mt++) for (int rg = 0; rg < 4; rg++){
      int row = mt*16 + q4*4 + rg;
      float p0 = 0.f, p1 = 0.f, p2 = 0.f;
      for (int nt = 0; nt < 4; nt++){
        float v = fmaxf(acc[mt][nt][rg] + bias[nt], 0.f);
        p0 += v*ow[nt][0]; p1 += v*ow[nt][1]; p2 += v*ow[nt][2];
      }
      for (int m = 1; m < 16; m <<= 1){
        p0 += __shfl_xor(p0, m, 64); p1 += __shfl_xor(p1, m, 64); p2 += __shfl_xor(p2, m, 64);
      }
      if (l15 == 0){
        pscr[w*192 + row*3 + 0] = p0;
        pscr[w*192 + row*3 + 1] = p1;
        pscr[w*192 + row*3 + 2] = p2;
      }
    }
  }
  PROJ_REDUCE;

  // ---- final store ----
  if (t < 192){
    int row = t / 3, o = t - (t/3)*3;
    int gr = rgp*64 + row;
    int b = gr & 7, q = gr >> 3;
    size_t idx = ((size_t)b*HWQ + q)*3 + o;
    if (*flag) ((float*)outv)[idx] = totrow[t];
    else       ((u16*)outv)[idx]   = f2bs(totrow[t]);
  }
}

extern "C" void kernel_launch(void* const* d_in, const int* in_sizes, int n_in,
                              void* d_out, int out_size, void* d_ws, size_t ws_size,
                              hipStream_t stream){
  (void)in_sizes; (void)n_in; (void)out_size;

  u16* wsp   = (u16*)d_ws;
  unsigned* flag = (unsigned*)wsp;
  u16* canon = wsp + 8;
  u16* WT    = canon + CANON_PAD;
  u16* kpart = WT + 1703936;
  u16* vT    = kpart + 262144;
  u16* qvecB = vT + 262144;
  u16* hlB   = qvecB + 2097152;
  u16* modB  = hlB + 25165824;
  if (ws_size < 199773250ULL) return;

  SrcPtrs sp;
  for (int i = 0; i < 16; i++) sp.p[i] = d_in[i];
  const float* xraw = (const float*)d_in[0];

  k_detect <<<1, 256, 0, stream>>>((const u16*)d_in[3], flag);
  k_convert<<<(C_TOTAL + 255)/256, 256, 0, stream>>>(sp, flag, canon);
  k_tr     <<<1664, 256, 0, stream>>>(canon, WT);
  k_kv     <<<2048, 256, 0, stream>>>(canon, kpart, vT);
  k_query  <<<1024, 256, 0, stream>>>(canon, xraw, flag, WT, qvecB, hlB);
  k_attn   <<<4096, 256, 0, stream>>>(canon, xraw, flag, qvecB, kpart, vT, WT, modB);
  k_bands3 <<<2048, 512, 0, stream>>>(canon, modB, WT, hlB, flag, d_out);
}